// Round 1
// baseline (2748.013 us; speedup 1.0000x reference)
//
#include <hip/hip_runtime.h>
#include <hip/hip_cooperative_groups.h>
#include <math.h>

namespace cg = cooperative_groups;

#define N_NODES  100000
#define N_INC    400000
#define N_EDGES  20000
#define N_GRAPHS 512
#define NSEQ     16
#define SLEN     32
#define F_IN     128
#define HID      256
#define RNN_H    256
#define ODIM     128

// ---------------- counting / CSR ----------------
__global__ void k_count(const int* __restrict__ he_node, const int* __restrict__ he_edge,
                        int* __restrict__ cnt_e, int* __restrict__ deg) {
  int i = blockIdx.x * 256 + threadIdx.x;
  if (i >= N_INC) return;
  atomicAdd(&cnt_e[he_edge[i]], 1);
  atomicAdd(&deg[he_node[i]], 1);
}

__global__ __launch_bounds__(1024)
void k_scan(const int* __restrict__ cnt, int* __restrict__ start, int n) {
  __shared__ int part[1024];
  int tid = threadIdx.x;
  int chunk = (n + 1023) / 1024;
  int lo = tid * chunk; if (lo > n) lo = n;
  int hi = lo + chunk;  if (hi > n) hi = n;
  int s = 0;
  for (int i = lo; i < hi; ++i) s += cnt[i];
  part[tid] = s;
  __syncthreads();
  for (int off = 1; off < 1024; off <<= 1) {
    int v = (tid >= off) ? part[tid - off] : 0;
    __syncthreads();
    part[tid] += v;
    __syncthreads();
  }
  int run = (tid == 0) ? 0 : part[tid - 1];
  for (int i = lo; i < hi; ++i) { start[i] = run; run += cnt[i]; }
  if (tid == 1023) start[n] = part[1023];
}

__global__ void k_fill(const int* __restrict__ he_node, const int* __restrict__ he_edge,
                       const int* __restrict__ e_start, const int* __restrict__ n_start,
                       int* __restrict__ cur_e, int* __restrict__ cur_n,
                       int* __restrict__ e_idx, int* __restrict__ n_idx) {
  int i = blockIdx.x * 256 + threadIdx.x;
  if (i >= N_INC) return;
  int e = he_edge[i]; int p = atomicAdd(&cur_e[e], 1); e_idx[e_start[e] + p] = i;
  int nn = he_node[i]; int q = atomicAdd(&cur_n[nn], 1); n_idx[n_start[nn] + q] = i;
}

__global__ void k_transpose(const float* __restrict__ in, float* __restrict__ out,
                            int rows, int cols) {
  int idx = blockIdx.x * 256 + threadIdx.x;
  if (idx >= rows * cols) return;
  int r = idx / cols, c = idx - r * cols;
  out[c * rows + r] = in[idx];
}

// ---------------- generic fp32 GEMM: C[M,N] = act(A[M,K] @ WT[N,K]^T + b1 + b2) ----------------
// block: 256 threads -> 32 rows x 256 cols. M % 32 == 0, K % 128 == 0.
__global__ __launch_bounds__(256)
void k_gemm(const float* __restrict__ A, const float* __restrict__ WT,
            float* __restrict__ C, int M, int N, int K,
            const float* __restrict__ bias1, const float* __restrict__ bias2,
            int act, int remap) {
  __shared__ float As[32][132];   // 132*4 = 528B stride, 16B aligned
  int m0 = blockIdx.y * 32;
  int c  = blockIdx.x * 256 + threadIdx.x;
  float acc[32];
#pragma unroll
  for (int r = 0; r < 32; ++r) acc[r] = 0.f;
  for (int kc = 0; kc < K; kc += 128) {
    for (int it = threadIdx.x; it < 1024; it += 256) {
      int r = it >> 5, c4 = it & 31;
      float4 v = *(const float4*)&A[(size_t)(m0 + r) * K + kc + c4 * 4];
      *(float4*)&As[r][c4 * 4] = v;
    }
    __syncthreads();
    if (c < N) {
      const float4* w4p = (const float4*)&WT[(size_t)c * K + kc];
#pragma unroll 4
      for (int k4 = 0; k4 < 32; ++k4) {
        float4 w = w4p[k4];
#pragma unroll
        for (int r = 0; r < 32; ++r) {
          float4 a = *(const float4*)&As[r][k4 * 4];
          acc[r] += a.x * w.x + a.y * w.y + a.z * w.z + a.w * w.w;
        }
      }
    }
    __syncthreads();
  }
  if (c >= N) return;
  float b = (bias1 ? bias1[c] : 0.f) + (bias2 ? bias2[c] : 0.f);
  for (int r = 0; r < 32; ++r) {
    float v = acc[r] + b;
    if (act == 1) v = fmaxf(v, 0.f);
    else if (act == 2) v = 1.f / (1.f + expf(-v));
    int row = m0 + r;
    int orow = remap ? ((row & 15) * 32 + (row >> 4)) : row;
    C[(size_t)orow * N + c] = v;
  }
}

// ---------------- hyperedge mean of raw node features ----------------
__global__ __launch_bounds__(128)
void k_eattr(const float* __restrict__ x, const int* __restrict__ he_node,
             const int* __restrict__ e_start, const int* __restrict__ e_idx,
             float* __restrict__ eattr) {
  int m = blockIdx.x, d = threadIdx.x;
  int begin = e_start[m], end = e_start[m + 1];
  float acc = 0.f;
  for (int j = begin; j < end; ++j)
    acc += x[(size_t)he_node[e_idx[j]] * F_IN + d];
  eattr[(size_t)m * F_IN + d] = acc / fmaxf((float)(end - begin), 1.f);
}

// ---------------- attention logits (one wave per incidence) ----------------
__global__ __launch_bounds__(256)
void k_alpha(const float* __restrict__ xh, const float* __restrict__ eh,
             const int* __restrict__ he_node, const int* __restrict__ he_edge,
             const float* __restrict__ att, float* __restrict__ alpha) {
  int i = blockIdx.x * 4 + (threadIdx.x >> 6);
  if (i >= N_INC) return;
  int lane = threadIdx.x & 63;
  int n = he_node[i], m = he_edge[i];
  const float* xr = &xh[(size_t)n * HID];
  const float* er = &eh[(size_t)m * HID];
  float p[4];
#pragma unroll
  for (int h = 0; h < 4; ++h)
    p[h] = xr[h * 64 + lane] * att[h * 128 + lane] + er[h * 64 + lane] * att[h * 128 + 64 + lane];
#pragma unroll
  for (int h = 0; h < 4; ++h) {
    float v = p[h];
    for (int off = 32; off; off >>= 1) v += __shfl_xor(v, off);
    p[h] = v;
  }
  if (lane == 0) {
    float4 o;
    o.x = p[0] > 0.f ? p[0] : 0.2f * p[0];
    o.y = p[1] > 0.f ? p[1] : 0.2f * p[1];
    o.z = p[2] > 0.f ? p[2] : 0.2f * p[2];
    o.w = p[3] > 0.f ? p[3] : 0.2f * p[3];
    *(float4*)&alpha[(size_t)i * 4] = o;
  }
}

// ---------------- per-hyperedge softmax (one wave per edge) ----------------
__global__ __launch_bounds__(256)
void k_softmax(const int* __restrict__ e_start, const int* __restrict__ e_idx,
               float* __restrict__ alpha) {
  int m = blockIdx.x * 4 + (threadIdx.x >> 6);
  if (m >= N_EDGES) return;
  int lane = threadIdx.x & 63;
  int begin = e_start[m], end = e_start[m + 1];
  int cnt = end - begin;
  if (cnt == 0) return;
  int nch = (cnt + 63) >> 6;
  float mx[4] = {-1e30f, -1e30f, -1e30f, -1e30f};
  for (int ch = 0; ch < nch; ++ch) {
    int j = begin + ch * 64 + lane;
    if (j < end) {
      float4 a = *(const float4*)&alpha[(size_t)e_idx[j] * 4];
      mx[0] = fmaxf(mx[0], a.x); mx[1] = fmaxf(mx[1], a.y);
      mx[2] = fmaxf(mx[2], a.z); mx[3] = fmaxf(mx[3], a.w);
    }
  }
#pragma unroll
  for (int h = 0; h < 4; ++h)
    for (int off = 32; off; off >>= 1) mx[h] = fmaxf(mx[h], __shfl_xor(mx[h], off));
  float s[4] = {0.f, 0.f, 0.f, 0.f};
  for (int ch = 0; ch < nch; ++ch) {
    int j = begin + ch * 64 + lane;
    if (j < end) {
      int i = e_idx[j];
      float4 a = *(const float4*)&alpha[(size_t)i * 4];
      a.x = expf(a.x - mx[0]); a.y = expf(a.y - mx[1]);
      a.z = expf(a.z - mx[2]); a.w = expf(a.w - mx[3]);
      *(float4*)&alpha[(size_t)i * 4] = a;
      s[0] += a.x; s[1] += a.y; s[2] += a.z; s[3] += a.w;
    }
  }
#pragma unroll
  for (int h = 0; h < 4; ++h) {
    for (int off = 32; off; off >>= 1) s[h] += __shfl_xor(s[h], off);
    s[h] = 1.f / fmaxf(s[h], 1e-16f);
  }
  for (int ch = 0; ch < nch; ++ch) {
    int j = begin + ch * 64 + lane;
    if (j < end) {
      int i = e_idx[j];
      float4 a = *(const float4*)&alpha[(size_t)i * 4];
      a.x *= s[0]; a.y *= s[1]; a.z *= s[2]; a.w *= s[3];
      *(float4*)&alpha[(size_t)i * 4] = a;
    }
  }
}

// ---------------- hop 1: node -> hyperedge ----------------
__global__ __launch_bounds__(256)
void k_out_e(const float* __restrict__ xh, const float* __restrict__ alpha,
             const int* __restrict__ e_start, const int* __restrict__ e_idx,
             const int* __restrict__ he_node, float* __restrict__ out_e) {
  int m = blockIdx.x, c = threadIdx.x, h = c >> 6;
  int begin = e_start[m], end = e_start[m + 1];
  float acc = 0.f;
  for (int j = begin; j < end; ++j) {
    int i = e_idx[j];
    acc += alpha[(size_t)i * 4 + h] * xh[(size_t)he_node[i] * HID + c];
  }
  float cnt = (float)(end - begin);
  float binv = cnt > 0.f ? 1.f / cnt : 0.f;
  out_e[(size_t)m * HID + c] = acc * binv;
}

// ---------------- hop 2: hyperedge -> node, + bias + relu ----------------
__global__ __launch_bounds__(256)
void k_out_n(const float* __restrict__ out_e, const float* __restrict__ alpha,
             const int* __restrict__ n_start, const int* __restrict__ n_idx,
             const int* __restrict__ he_edge, const float* __restrict__ bias,
             float* __restrict__ hout) {
  int n = blockIdx.x, c = threadIdx.x, h = c >> 6;
  int begin = n_start[n], end = n_start[n + 1];
  float acc = 0.f;
  for (int j = begin; j < end; ++j) {
    int i = n_idx[j];
    acc += alpha[(size_t)i * 4 + h] * out_e[(size_t)he_edge[i] * HID + c];
  }
  float d = (float)(end - begin);
  float dinv = d > 0.f ? 1.f / d : 0.f;
  float v = acc * dinv + bias[c];
  hout[(size_t)n * HID + c] = fmaxf(v, 0.f);
}

// ---------------- graph segment starts (batch is sorted) ----------------
__global__ void k_gstart(const int* __restrict__ batch, int* __restrict__ gs) {
  int g = blockIdx.x * 256 + threadIdx.x;
  if (g > N_GRAPHS) return;
  int lo = 0, hi = N_NODES;
  while (lo < hi) { int mid = (lo + hi) >> 1; if (batch[mid] < g) lo = mid + 1; else hi = mid; }
  gs[g] = lo;
}

__global__ __launch_bounds__(256)
void k_pool(const float* __restrict__ h, const int* __restrict__ gs,
            float* __restrict__ pooled) {
  int g = blockIdx.x, c = threadIdx.x;
  int begin = gs[g], end = gs[g + 1];
  float acc = 0.f;
  for (int n = begin; n < end; ++n) acc += h[(size_t)n * HID + c];
  pooled[(size_t)g * HID + c] = acc / fmaxf((float)(end - begin), 1.f);
}

// ---------------- BiLSTM recurrence (cooperative, one launch per layer) ----------------
// grid: 64 blocks = 2 dir x 32 hid-chunks; block: 128 threads = 16 b x 8 hid.
// xg holds x@w_ih^T + b_ih + b_hh, laid out [xrow][2048] with col = dir*1024 + gate*256 + hid.
// xrow = b*rsb + t*rst. out rows are t*16+b, cols dir*256+hid.
__global__ __launch_bounds__(128)
void k_lstm(const float* __restrict__ xg, const float* __restrict__ w_hh,
            float* __restrict__ out, float* __restrict__ hbuf,
            int rst, int rsb) {
  __shared__ float4 wsf4[64 * 4 * 8];   // [k4][gate][hl] -> 32 KB, conflict-free
  int dir = blockIdx.x >> 5, hc = blockIdx.x & 31;
  int tid = threadIdx.x;
  int hl = tid & 7, b = tid >> 3;
  int hid = hc * 8 + hl;
  for (int it = tid; it < 2048; it += 128) {
    int r = it >> 6, k4 = it & 63;
    int gate = r >> 3, rr = r & 7;
    float4 v = *(const float4*)&w_hh[((size_t)dir * 1024 + gate * 256 + hc * 8 + rr) * 256 + k4 * 4];
    wsf4[(k4 * 4 + gate) * 8 + rr] = v;
  }
  __syncthreads();
  cg::grid_group grid = cg::this_grid();
  float cr = 0.f;
  for (int t = 0; t < 32; ++t) {
    int te = dir ? (31 - t) : t;
    int xrow = b * rsb + te * rst;
    const float* xgp = &xg[(size_t)xrow * 2048 + dir * 1024 + hid];
    float g0 = xgp[0], g1 = xgp[256], g2 = xgp[512], g3 = xgp[768];
    if (t > 0) {
      const float4* hp = (const float4*)&hbuf[(size_t)((t & 1) * 32 + dir * 16 + b) * 256];
#pragma unroll 8
      for (int k4 = 0; k4 < 64; ++k4) {
        float4 hv = hp[k4];
        float4 w0 = wsf4[(k4 * 4 + 0) * 8 + hl];
        float4 w1 = wsf4[(k4 * 4 + 1) * 8 + hl];
        float4 w2 = wsf4[(k4 * 4 + 2) * 8 + hl];
        float4 w3 = wsf4[(k4 * 4 + 3) * 8 + hl];
        g0 += hv.x * w0.x + hv.y * w0.y + hv.z * w0.z + hv.w * w0.w;
        g1 += hv.x * w1.x + hv.y * w1.y + hv.z * w1.z + hv.w * w1.w;
        g2 += hv.x * w2.x + hv.y * w2.y + hv.z * w2.z + hv.w * w2.w;
        g3 += hv.x * w3.x + hv.y * w3.y + hv.z * w3.z + hv.w * w3.w;
      }
    }
    float ig = 1.f / (1.f + expf(-g0));
    float fg = 1.f / (1.f + expf(-g1));
    float gg = tanhf(g2);
    float og = 1.f / (1.f + expf(-g3));
    cr = fg * cr + ig * gg;
    float hv = og * tanhf(cr);
    hbuf[(size_t)(((t + 1) & 1) * 32 + dir * 16 + b) * 256 + hid] = hv;
    out[((size_t)te * 16 + b) * 512 + dir * 256 + hid] = hv;
    grid.sync();
  }
}

// ---------------- launch ----------------
extern "C" void kernel_launch(void* const* d_in, const int* in_sizes, int n_in,
                              void* d_out, int out_size, void* d_ws, size_t ws_size,
                              hipStream_t stream) {
  const float* x        = (const float*)d_in[0];
  const int*   he_node  = (const int*)d_in[1];
  const int*   he_edge  = (const int*)d_in[2];
  const int*   batch    = (const int*)d_in[3];
  const float* w_lin    = (const float*)d_in[4];
  const float* att      = (const float*)d_in[5];
  const float* bias     = (const float*)d_in[6];
  const float* w_ih0    = (const float*)d_in[7];
  const float* w_hh0    = (const float*)d_in[8];
  const float* b_ih0    = (const float*)d_in[9];
  const float* b_hh0    = (const float*)d_in[10];
  const float* w_ih1    = (const float*)d_in[11];
  const float* w_hh1    = (const float*)d_in[12];
  const float* b_ih1    = (const float*)d_in[13];
  const float* b_hh1    = (const float*)d_in[14];
  const float* w_causal = (const float*)d_in[15];
  const float* b_causal = (const float*)d_in[16];
  const float* w_link   = (const float*)d_in[17];
  const float* b_link   = (const float*)d_in[18];
  float* out = (float*)d_out;

  char* ws = (char*)d_ws;
  size_t off = 0;
  auto alloc = [&](size_t bytes) -> void* {
    void* p = ws + off;
    off = (off + bytes + 255) & ~(size_t)255;
    return p;
  };
  float* xh      = (float*)alloc((size_t)N_NODES * HID * 4);   // reused as h after out_e
  float* eattr   = (float*)alloc((size_t)N_EDGES * F_IN * 4);
  float* eh      = (float*)alloc((size_t)N_EDGES * HID * 4);
  float* alpha   = (float*)alloc((size_t)N_INC * 4 * 4);
  float* out_e   = (float*)alloc((size_t)N_EDGES * HID * 4);
  int*   cnt_e   = (int*)alloc(N_EDGES * 4);
  int*   deg     = (int*)alloc(N_NODES * 4);
  int*   e_start = (int*)alloc((N_EDGES + 1) * 4);
  int*   n_start = (int*)alloc((N_NODES + 1) * 4);
  int*   cur_e   = (int*)alloc(N_EDGES * 4);
  int*   cur_n   = (int*)alloc(N_NODES * 4);
  int*   e_idx   = (int*)alloc(N_INC * 4);
  int*   n_idx   = (int*)alloc(N_INC * 4);
  int*   gstart  = (int*)alloc((N_GRAPHS + 1) * 4);
  float* pooled  = (float*)alloc((size_t)N_GRAPHS * HID * 4);
  float* wlinT   = (float*)alloc((size_t)HID * F_IN * 4);
  float* wcT     = (float*)alloc((size_t)HID * 512 * 4);
  float* wlkT    = (float*)alloc((size_t)ODIM * HID * 4);
  float* xg1     = (float*)alloc((size_t)512 * 2048 * 4);
  float* xg2     = (float*)alloc((size_t)512 * 2048 * 4);
  float* l1      = (float*)alloc((size_t)512 * 512 * 4);
  float* l2      = (float*)alloc((size_t)512 * 512 * 4);
  float* causal  = (float*)alloc((size_t)512 * HID * 4);
  float* hbuf    = (float*)alloc((size_t)2 * 2 * 16 * 256 * 4);

  hipMemsetAsync(cnt_e, 0, N_EDGES * 4, stream);
  hipMemsetAsync(deg,   0, N_NODES * 4, stream);
  hipMemsetAsync(cur_e, 0, N_EDGES * 4, stream);
  hipMemsetAsync(cur_n, 0, N_NODES * 4, stream);

  // CSR build
  k_count<<<(N_INC + 255) / 256, 256, 0, stream>>>(he_node, he_edge, cnt_e, deg);
  k_scan<<<1, 1024, 0, stream>>>(cnt_e, e_start, N_EDGES);
  k_scan<<<1, 1024, 0, stream>>>(deg, n_start, N_NODES);
  k_fill<<<(N_INC + 255) / 256, 256, 0, stream>>>(he_node, he_edge, e_start, n_start,
                                                  cur_e, cur_n, e_idx, n_idx);
  // weight transposes
  k_transpose<<<(F_IN * HID + 255) / 256, 256, 0, stream>>>(w_lin, wlinT, F_IN, HID);
  k_transpose<<<(512 * HID + 255) / 256, 256, 0, stream>>>(w_causal, wcT, 512, HID);
  k_transpose<<<(HID * ODIM + 255) / 256, 256, 0, stream>>>(w_link, wlkT, HID, ODIM);

  // xh = x @ w_lin
  k_gemm<<<dim3(1, N_NODES / 32), 256, 0, stream>>>(x, wlinT, xh, N_NODES, HID, F_IN,
                                                    nullptr, nullptr, 0, 0);
  // eattr (hyperedge mean) and eh = eattr @ w_lin
  k_eattr<<<N_EDGES, 128, 0, stream>>>(x, he_node, e_start, e_idx, eattr);
  k_gemm<<<dim3(1, N_EDGES / 32), 256, 0, stream>>>(eattr, wlinT, eh, N_EDGES, HID, F_IN,
                                                    nullptr, nullptr, 0, 0);
  // attention
  k_alpha<<<N_INC / 4, 256, 0, stream>>>(xh, eh, he_node, he_edge, att, alpha);
  k_softmax<<<N_EDGES / 4, 256, 0, stream>>>(e_start, e_idx, alpha);
  // two-hop propagation
  k_out_e<<<N_EDGES, 256, 0, stream>>>(xh, alpha, e_start, e_idx, he_node, out_e);
  k_out_n<<<N_NODES, 256, 0, stream>>>(out_e, alpha, n_start, n_idx, he_edge, bias, xh /*=h*/);
  // pooling
  k_gstart<<<(N_GRAPHS + 1 + 255) / 256, 256, 0, stream>>>(batch, gstart);
  k_pool<<<N_GRAPHS, 256, 0, stream>>>(xh /*=h*/, gstart, pooled);

  // LSTM layer 1: xg1[g=b*32+t][dir*1024+gate*256+hid]
  k_gemm<<<dim3(8, 512 / 32), 256, 0, stream>>>(pooled, w_ih0, xg1, 512, 2048, HID,
                                                b_ih0, b_hh0, 0, 0);
  {
    const float* a0 = xg1; const float* a1 = w_hh0; float* a2 = l1; float* a3 = hbuf;
    int rst = 1, rsb = 32;
    void* args[] = {&a0, &a1, &a2, &a3, &rst, &rsb};
    hipLaunchCooperativeKernel((void*)k_lstm, dim3(64), dim3(128), args, 0, stream);
  }
  // LSTM layer 2: xg2 rows = t*16+b (l1 layout)
  k_gemm<<<dim3(8, 512 / 32), 256, 0, stream>>>(l1, w_ih1, xg2, 512, 2048, 512,
                                                b_ih1, b_hh1, 0, 0);
  {
    const float* a0 = xg2; const float* a1 = w_hh1; float* a2 = l2; float* a3 = hbuf;
    int rst = 16, rsb = 1;
    void* args[] = {&a0, &a1, &a2, &a3, &rst, &rsb};
    hipLaunchCooperativeKernel((void*)k_lstm, dim3(64), dim3(128), args, 0, stream);
  }
  // heads
  k_gemm<<<dim3(1, 512 / 32), 256, 0, stream>>>(l2, wcT, causal, 512, HID, 512,
                                                b_causal, nullptr, 1, 0);
  k_gemm<<<dim3(1, 512 / 32), 256, 0, stream>>>(causal, wlkT, out, 512, ODIM, HID,
                                                b_link, nullptr, 2, 1);
  (void)in_sizes; (void)n_in; (void)out_size; (void)ws_size;
}

// Round 3
// 2161.027 us; speedup vs baseline: 1.2716x; 1.2716x over previous
//
#include <hip/hip_runtime.h>
#include <math.h>

#define N_NODES  100000
#define N_INC    400000
#define N_EDGES  20000
#define N_GRAPHS 512
#define F_IN     128
#define HID      256
#define RNN_H    256
#define ODIM     128

// ---------------- counting / CSR ----------------
__global__ void k_count(const int* __restrict__ he_node, const int* __restrict__ he_edge,
                        int* __restrict__ cnt_e, int* __restrict__ deg) {
  int i = blockIdx.x * 256 + threadIdx.x;
  if (i >= N_INC) return;
  atomicAdd(&cnt_e[he_edge[i]], 1);
  atomicAdd(&deg[he_node[i]], 1);
}

__global__ __launch_bounds__(1024)
void k_scan(const int* __restrict__ cnt, int* __restrict__ start, int n) {
  __shared__ int part[1024];
  int tid = threadIdx.x;
  int chunk = (n + 1023) / 1024;
  int lo = tid * chunk; if (lo > n) lo = n;
  int hi = lo + chunk;  if (hi > n) hi = n;
  int s = 0;
  for (int i = lo; i < hi; ++i) s += cnt[i];
  part[tid] = s;
  __syncthreads();
  for (int off = 1; off < 1024; off <<= 1) {
    int v = (tid >= off) ? part[tid - off] : 0;
    __syncthreads();
    part[tid] += v;
    __syncthreads();
  }
  int run = (tid == 0) ? 0 : part[tid - 1];
  for (int i = lo; i < hi; ++i) { start[i] = run; run += cnt[i]; }
  if (tid == 1023) start[n] = part[1023];
}

__global__ void k_fill(const int* __restrict__ he_node, const int* __restrict__ he_edge,
                       const int* __restrict__ e_start, const int* __restrict__ n_start,
                       int* __restrict__ cur_e, int* __restrict__ cur_n,
                       int* __restrict__ e_idx, int* __restrict__ n_idx) {
  int i = blockIdx.x * 256 + threadIdx.x;
  if (i >= N_INC) return;
  int e = he_edge[i]; int p = atomicAdd(&cur_e[e], 1); e_idx[e_start[e] + p] = i;
  int nn = he_node[i]; int q = atomicAdd(&cur_n[nn], 1); n_idx[n_start[nn] + q] = i;
}

__global__ void k_transpose(const float* __restrict__ in, float* __restrict__ out,
                            int rows, int cols) {
  int idx = blockIdx.x * 256 + threadIdx.x;
  if (idx >= rows * cols) return;
  int r = idx / cols, c = idx - r * cols;
  out[c * rows + r] = in[idx];
}

// ---------------- generic fp32 GEMM: C[M,N] = act(A[M,K] @ WT[N,K]^T + b1 + b2) ----------------
__global__ __launch_bounds__(256)
void k_gemm(const float* __restrict__ A, const float* __restrict__ WT,
            float* __restrict__ C, int M, int N, int K,
            const float* __restrict__ bias1, const float* __restrict__ bias2,
            int act, int remap) {
  __shared__ float As[32][132];
  int m0 = blockIdx.y * 32;
  int c  = blockIdx.x * 256 + threadIdx.x;
  float acc[32];
#pragma unroll
  for (int r = 0; r < 32; ++r) acc[r] = 0.f;
  for (int kc = 0; kc < K; kc += 128) {
    for (int it = threadIdx.x; it < 1024; it += 256) {
      int r = it >> 5, c4 = it & 31;
      float4 v = *(const float4*)&A[(size_t)(m0 + r) * K + kc + c4 * 4];
      *(float4*)&As[r][c4 * 4] = v;
    }
    __syncthreads();
    if (c < N) {
      const float4* w4p = (const float4*)&WT[(size_t)c * K + kc];
#pragma unroll 4
      for (int k4 = 0; k4 < 32; ++k4) {
        float4 w = w4p[k4];
#pragma unroll
        for (int r = 0; r < 32; ++r) {
          float4 a = *(const float4*)&As[r][k4 * 4];
          acc[r] += a.x * w.x + a.y * w.y + a.z * w.z + a.w * w.w;
        }
      }
    }
    __syncthreads();
  }
  if (c >= N) return;
  float b = (bias1 ? bias1[c] : 0.f) + (bias2 ? bias2[c] : 0.f);
  for (int r = 0; r < 32; ++r) {
    float v = acc[r] + b;
    if (act == 1) v = fmaxf(v, 0.f);
    else if (act == 2) v = 1.f / (1.f + expf(-v));
    int row = m0 + r;
    int orow = remap ? ((row & 15) * 32 + (row >> 4)) : row;
    C[(size_t)orow * N + c] = v;
  }
}

// ---------------- hyperedge mean of raw node features (wave per edge) ----------------
__global__ __launch_bounds__(256)
void k_eattr(const float* __restrict__ x, const int* __restrict__ he_node,
             const int* __restrict__ e_start, const int* __restrict__ e_idx,
             float* __restrict__ eattr) {
  int m = blockIdx.x * 4 + (threadIdx.x >> 6);
  if (m >= N_EDGES) return;
  int lane = threadIdx.x & 63;
  int c4 = lane & 31, jp = lane >> 5;
  int begin = e_start[m], end = e_start[m + 1];
  float4 acc = {0.f, 0.f, 0.f, 0.f};
  for (int j = begin + jp; j < end; j += 2) {
    float4 v = *(const float4*)&x[(size_t)he_node[e_idx[j]] * F_IN + c4 * 4];
    acc.x += v.x; acc.y += v.y; acc.z += v.z; acc.w += v.w;
  }
  acc.x += __shfl_xor(acc.x, 32); acc.y += __shfl_xor(acc.y, 32);
  acc.z += __shfl_xor(acc.z, 32); acc.w += __shfl_xor(acc.w, 32);
  if (jp == 0) {
    float inv = 1.f / fmaxf((float)(end - begin), 1.f);
    float4 o = {acc.x * inv, acc.y * inv, acc.z * inv, acc.w * inv};
    *(float4*)&eattr[(size_t)m * F_IN + c4 * 4] = o;
  }
}

// ---------------- separable attention: per-row dot with att half ----------------
__global__ __launch_bounds__(256)
void k_dot(const float* __restrict__ X, const float* __restrict__ att,
           float* __restrict__ s, int half, int nrows) {
  int row = blockIdx.x * 4 + (threadIdx.x >> 6);
  if (row >= nrows) return;
  int lane = threadIdx.x & 63;
  int h = lane >> 4;
  float4 v = *(const float4*)&X[(size_t)row * HID + lane * 4];
  float4 a = *(const float4*)&att[h * 128 + half * 64 + (lane & 15) * 4];
  float p = v.x * a.x + v.y * a.y + v.z * a.z + v.w * a.w;
  p += __shfl_xor(p, 1); p += __shfl_xor(p, 2);
  p += __shfl_xor(p, 4); p += __shfl_xor(p, 8);
  if ((lane & 15) == 0) s[(size_t)row * 4 + h] = p;
}

// ---------------- logits: gather s_n + s_e, leaky relu ----------------
__global__ void k_logit(const int* __restrict__ he_node, const int* __restrict__ he_edge,
                        const float* __restrict__ s_n, const float* __restrict__ s_e,
                        float* __restrict__ alpha) {
  int i = blockIdx.x * 256 + threadIdx.x;
  if (i >= N_INC) return;
  float4 a = *(const float4*)&s_n[(size_t)he_node[i] * 4];
  float4 b = *(const float4*)&s_e[(size_t)he_edge[i] * 4];
  float4 o;
  o.x = a.x + b.x; o.y = a.y + b.y; o.z = a.z + b.z; o.w = a.w + b.w;
  o.x = o.x > 0.f ? o.x : 0.2f * o.x;
  o.y = o.y > 0.f ? o.y : 0.2f * o.y;
  o.z = o.z > 0.f ? o.z : 0.2f * o.z;
  o.w = o.w > 0.f ? o.w : 0.2f * o.w;
  *(float4*)&alpha[(size_t)i * 4] = o;
}

// ---------------- per-hyperedge softmax (one wave per edge) ----------------
__global__ __launch_bounds__(256)
void k_softmax(const int* __restrict__ e_start, const int* __restrict__ e_idx,
               float* __restrict__ alpha) {
  int m = blockIdx.x * 4 + (threadIdx.x >> 6);
  if (m >= N_EDGES) return;
  int lane = threadIdx.x & 63;
  int begin = e_start[m], end = e_start[m + 1];
  int cnt = end - begin;
  if (cnt == 0) return;
  int nch = (cnt + 63) >> 6;
  float mx[4] = {-1e30f, -1e30f, -1e30f, -1e30f};
  for (int ch = 0; ch < nch; ++ch) {
    int j = begin + ch * 64 + lane;
    if (j < end) {
      float4 a = *(const float4*)&alpha[(size_t)e_idx[j] * 4];
      mx[0] = fmaxf(mx[0], a.x); mx[1] = fmaxf(mx[1], a.y);
      mx[2] = fmaxf(mx[2], a.z); mx[3] = fmaxf(mx[3], a.w);
    }
  }
#pragma unroll
  for (int h = 0; h < 4; ++h)
    for (int off = 32; off; off >>= 1) mx[h] = fmaxf(mx[h], __shfl_xor(mx[h], off));
  float s[4] = {0.f, 0.f, 0.f, 0.f};
  for (int ch = 0; ch < nch; ++ch) {
    int j = begin + ch * 64 + lane;
    if (j < end) {
      int i = e_idx[j];
      float4 a = *(const float4*)&alpha[(size_t)i * 4];
      a.x = expf(a.x - mx[0]); a.y = expf(a.y - mx[1]);
      a.z = expf(a.z - mx[2]); a.w = expf(a.w - mx[3]);
      *(float4*)&alpha[(size_t)i * 4] = a;
      s[0] += a.x; s[1] += a.y; s[2] += a.z; s[3] += a.w;
    }
  }
#pragma unroll
  for (int h = 0; h < 4; ++h) {
    for (int off = 32; off; off >>= 1) s[h] += __shfl_xor(s[h], off);
    s[h] = 1.f / fmaxf(s[h], 1e-16f);
  }
  for (int ch = 0; ch < nch; ++ch) {
    int j = begin + ch * 64 + lane;
    if (j < end) {
      int i = e_idx[j];
      float4 a = *(const float4*)&alpha[(size_t)i * 4];
      a.x *= s[0]; a.y *= s[1]; a.z *= s[2]; a.w *= s[3];
      *(float4*)&alpha[(size_t)i * 4] = a;
    }
  }
}

// ---------------- hop 1: node -> hyperedge (wave per edge) ----------------
__global__ __launch_bounds__(256)
void k_out_e(const float* __restrict__ xh, const float* __restrict__ alpha,
             const int* __restrict__ e_start, const int* __restrict__ e_idx,
             const int* __restrict__ he_node, float* __restrict__ out_e) {
  int m = blockIdx.x * 4 + (threadIdx.x >> 6);
  if (m >= N_EDGES) return;
  int lane = threadIdx.x & 63, h = lane >> 4;
  int begin = e_start[m], end = e_start[m + 1];
  float4 acc = {0.f, 0.f, 0.f, 0.f};
  for (int j = begin; j < end; ++j) {
    int i = e_idx[j];
    float a = alpha[(size_t)i * 4 + h];
    float4 v = *(const float4*)&xh[(size_t)he_node[i] * HID + lane * 4];
    acc.x += a * v.x; acc.y += a * v.y; acc.z += a * v.z; acc.w += a * v.w;
  }
  float bi = (end > begin) ? 1.f / (float)(end - begin) : 0.f;
  float4 o = {acc.x * bi, acc.y * bi, acc.z * bi, acc.w * bi};
  *(float4*)&out_e[(size_t)m * HID + lane * 4] = o;
}

// ---------------- hop 2: hyperedge -> node, + bias + relu (wave per node) ----------------
__global__ __launch_bounds__(256)
void k_out_n(const float* __restrict__ out_e, const float* __restrict__ alpha,
             const int* __restrict__ n_start, const int* __restrict__ n_idx,
             const int* __restrict__ he_edge, const float* __restrict__ bias,
             float* __restrict__ hout) {
  int n = blockIdx.x * 4 + (threadIdx.x >> 6);
  if (n >= N_NODES) return;
  int lane = threadIdx.x & 63, h = lane >> 4;
  int begin = n_start[n], end = n_start[n + 1];
  float4 acc = {0.f, 0.f, 0.f, 0.f};
  for (int j = begin; j < end; ++j) {
    int i = n_idx[j];
    float a = alpha[(size_t)i * 4 + h];
    float4 v = *(const float4*)&out_e[(size_t)he_edge[i] * HID + lane * 4];
    acc.x += a * v.x; acc.y += a * v.y; acc.z += a * v.z; acc.w += a * v.w;
  }
  float di = (end > begin) ? 1.f / (float)(end - begin) : 0.f;
  float4 bb = *(const float4*)&bias[lane * 4];
  float4 o;
  o.x = fmaxf(acc.x * di + bb.x, 0.f);
  o.y = fmaxf(acc.y * di + bb.y, 0.f);
  o.z = fmaxf(acc.z * di + bb.z, 0.f);
  o.w = fmaxf(acc.w * di + bb.w, 0.f);
  *(float4*)&hout[(size_t)n * HID + lane * 4] = o;
}

// ---------------- graph segment starts (batch is sorted) ----------------
__global__ void k_gstart(const int* __restrict__ batch, int* __restrict__ gs) {
  int g = blockIdx.x * 256 + threadIdx.x;
  if (g > N_GRAPHS) return;
  int lo = 0, hi = N_NODES;
  while (lo < hi) { int mid = (lo + hi) >> 1; if (batch[mid] < g) lo = mid + 1; else hi = mid; }
  gs[g] = lo;
}

__global__ __launch_bounds__(256)
void k_pool(const float* __restrict__ h, const int* __restrict__ gs,
            float* __restrict__ pooled) {
  __shared__ float4 part[4][64];
  int g = blockIdx.x, tid = threadIdx.x;
  int rs = tid >> 6, c4 = tid & 63;
  int begin = gs[g], end = gs[g + 1];
  float4 acc = {0.f, 0.f, 0.f, 0.f};
  for (int n = begin + rs; n < end; n += 4) {
    float4 v = *(const float4*)&h[(size_t)n * HID + c4 * 4];
    acc.x += v.x; acc.y += v.y; acc.z += v.z; acc.w += v.w;
  }
  part[rs][c4] = acc;
  __syncthreads();
  if (rs == 0) {
    float4 a = part[0][c4], b = part[1][c4], c = part[2][c4], d = part[3][c4];
    float inv = 1.f / fmaxf((float)(end - begin), 1.f);
    float4 o = {(a.x + b.x + c.x + d.x) * inv, (a.y + b.y + c.y + d.y) * inv,
                (a.z + b.z + c.z + d.z) * inv, (a.w + b.w + c.w + d.w) * inv};
    *(float4*)&pooled[(size_t)g * HID + c4 * 4] = o;
  }
}

// ---------------- BiLSTM recurrence: 32 blocks, custom per-direction barrier ----------------
__global__ __launch_bounds__(256)
void k_lstm2(const float* __restrict__ xg, const float* __restrict__ w_hh,
             float* __restrict__ out, float* __restrict__ hbuf,
             int* __restrict__ lc, int rst, int rsb) {
  __shared__ float4 ws4[64][64];   // 64 KB exactly
  const int dir = blockIdx.x >> 4, q = blockIdx.x & 15;
  const int tid = threadIdx.x;
  const int l = tid & 63, w = tid >> 6;
  const int ks = l & 3, rg = l >> 2;

  // stage w_hh rows (4 gates x 16 hid) with bank-balancing XOR swizzle
  for (int it = tid; it < 4096; it += 256) {
    int row = it >> 6, c4 = it & 63;         // row = g*16 + r
    int g = row >> 4, r = row & 15;
    float4 v = *(const float4*)&w_hh[((size_t)dir * 1024 + g * 256 + q * 16 + r) * 256 + c4 * 4];
    ws4[row][c4 ^ ((c4 >> 4) & 3) ^ (r & 7)] = v;
  }
  __syncthreads();

  float c[4] = {0.f, 0.f, 0.f, 0.f};
  for (int t = 0; t < 32; ++t) {
    const int te = dir ? (31 - t) : t;
    const float* hprev = hbuf + ((size_t)(t & 1) * 2 + dir) * 16 * 256;
    float acc[4][4];
#pragma unroll
    for (int g = 0; g < 4; ++g)
#pragma unroll
      for (int lb = 0; lb < 4; ++lb) acc[g][lb] = 0.f;
#pragma unroll
    for (int j = 0; j < 16; ++j) {
      int col = ks * 16 + j;
      float4 h4[4];
#pragma unroll
      for (int lb = 0; lb < 4; ++lb)
        h4[lb] = *(const float4*)&hprev[(w * 4 + lb) * 256 + col * 4];
      int csw = col ^ ks ^ (rg & 7);
#pragma unroll
      for (int g = 0; g < 4; ++g) {
        float4 wv = ws4[g * 16 + rg][csw];
#pragma unroll
        for (int lb = 0; lb < 4; ++lb)
          acc[g][lb] += wv.x * h4[lb].x + wv.y * h4[lb].y + wv.z * h4[lb].z + wv.w * h4[lb].w;
      }
    }
#pragma unroll
    for (int g = 0; g < 4; ++g)
#pragma unroll
      for (int lb = 0; lb < 4; ++lb) {
        float v = acc[g][lb];
        v += __shfl_xor(v, 1);
        v += __shfl_xor(v, 2);
        acc[g][lb] = v;
      }
    float hv[4];
#pragma unroll
    for (int lb = 0; lb < 4; ++lb) {
      int b = w * 4 + lb;
      const float* xp = &xg[(size_t)(b * rsb + te * rst) * 2048 + dir * 1024 + q * 16 + rg];
      float gi = acc[0][lb] + xp[0];
      float gf = acc[1][lb] + xp[256];
      float gg = acc[2][lb] + xp[512];
      float go = acc[3][lb] + xp[768];
      gi = 1.f / (1.f + expf(-gi));
      gf = 1.f / (1.f + expf(-gf));
      gg = tanhf(gg);
      go = 1.f / (1.f + expf(-go));
      c[lb] = gf * c[lb] + gi * gg;
      hv[lb] = go * tanhf(c[lb]);
    }
    float* hnext = hbuf + ((size_t)((t + 1) & 1) * 2 + dir) * 16 * 256;
    if (ks == 0) {
#pragma unroll
      for (int lb = 0; lb < 4; ++lb) {
        int b = w * 4 + lb;
        hnext[b * 256 + q * 16 + rg] = hv[lb];
        out[((size_t)te * 16 + b) * 512 + dir * 256 + q * 16 + rg] = hv[lb];
      }
    }
    if (t < 31) {
      __syncthreads();  // drains this block's stores (vmcnt 0 at barrier)
      if (tid == 0) {
        __builtin_amdgcn_fence(__ATOMIC_RELEASE, "agent");   // flush XCD L2
        __hip_atomic_fetch_add(&lc[dir * 32 + t], 1, __ATOMIC_RELAXED, __HIP_MEMORY_SCOPE_AGENT);
        while (__hip_atomic_load(&lc[dir * 32 + t], __ATOMIC_RELAXED, __HIP_MEMORY_SCOPE_AGENT) < 16)
          __builtin_amdgcn_s_sleep(2);
      }
      __syncthreads();
      __builtin_amdgcn_fence(__ATOMIC_ACQUIRE, "agent");     // invalidate before h reads
    }
  }
}

// ---------------- launch ----------------
extern "C" void kernel_launch(void* const* d_in, const int* in_sizes, int n_in,
                              void* d_out, int out_size, void* d_ws, size_t ws_size,
                              hipStream_t stream) {
  const float* x        = (const float*)d_in[0];
  const int*   he_node  = (const int*)d_in[1];
  const int*   he_edge  = (const int*)d_in[2];
  const int*   batch    = (const int*)d_in[3];
  const float* w_lin    = (const float*)d_in[4];
  const float* att      = (const float*)d_in[5];
  const float* bias     = (const float*)d_in[6];
  const float* w_ih0    = (const float*)d_in[7];
  const float* w_hh0    = (const float*)d_in[8];
  const float* b_ih0    = (const float*)d_in[9];
  const float* b_hh0    = (const float*)d_in[10];
  const float* w_ih1    = (const float*)d_in[11];
  const float* w_hh1    = (const float*)d_in[12];
  const float* b_ih1    = (const float*)d_in[13];
  const float* b_hh1    = (const float*)d_in[14];
  const float* w_causal = (const float*)d_in[15];
  const float* b_causal = (const float*)d_in[16];
  const float* w_link   = (const float*)d_in[17];
  const float* b_link   = (const float*)d_in[18];
  float* out = (float*)d_out;

  char* ws = (char*)d_ws;
  size_t off = 0;
  auto alloc = [&](size_t bytes) -> void* {
    void* p = ws + off;
    off = (off + bytes + 255) & ~(size_t)255;
    return p;
  };
  float* xh      = (float*)alloc((size_t)N_NODES * HID * 4);   // reused as h after out_n
  float* eattr   = (float*)alloc((size_t)N_EDGES * F_IN * 4);
  float* eh      = (float*)alloc((size_t)N_EDGES * HID * 4);
  float* alpha   = (float*)alloc((size_t)N_INC * 4 * 4);
  float* out_e   = (float*)alloc((size_t)N_EDGES * HID * 4);
  float* s_n     = (float*)alloc((size_t)N_NODES * 4 * 4);
  float* s_e     = (float*)alloc((size_t)N_EDGES * 4 * 4);
  int*   cnt_e   = (int*)alloc(N_EDGES * 4);
  int*   deg     = (int*)alloc(N_NODES * 4);
  int*   e_start = (int*)alloc((N_EDGES + 1) * 4);
  int*   n_start = (int*)alloc((N_NODES + 1) * 4);
  int*   cur_e   = (int*)alloc(N_EDGES * 4);
  int*   cur_n   = (int*)alloc(N_NODES * 4);
  int*   e_idx   = (int*)alloc(N_INC * 4);
  int*   n_idx   = (int*)alloc(N_INC * 4);
  int*   gstart  = (int*)alloc((N_GRAPHS + 1) * 4);
  float* pooled  = (float*)alloc((size_t)N_GRAPHS * HID * 4);
  float* wlinT   = (float*)alloc((size_t)HID * F_IN * 4);
  float* wcT     = (float*)alloc((size_t)HID * 512 * 4);
  float* wlkT    = (float*)alloc((size_t)ODIM * HID * 4);
  float* xg1     = (float*)alloc((size_t)512 * 2048 * 4);
  float* xg2     = (float*)alloc((size_t)512 * 2048 * 4);
  float* l1      = (float*)alloc((size_t)512 * 512 * 4);
  float* l2      = (float*)alloc((size_t)512 * 512 * 4);
  float* causal  = (float*)alloc((size_t)512 * HID * 4);
  float* hbuf    = (float*)alloc((size_t)2 * 2 * 2 * 16 * 256 * 4);  // [layer][slot][dir][b][256]
  int*   lcnt    = (int*)alloc(2 * 64 * 4);

  hipMemsetAsync(cnt_e, 0, N_EDGES * 4, stream);
  hipMemsetAsync(deg,   0, N_NODES * 4, stream);
  hipMemsetAsync(cur_e, 0, N_EDGES * 4, stream);
  hipMemsetAsync(cur_n, 0, N_NODES * 4, stream);
  hipMemsetAsync(hbuf,  0, (size_t)2 * 2 * 2 * 16 * 256 * 4, stream);
  hipMemsetAsync(lcnt,  0, 2 * 64 * 4, stream);

  // CSR build
  k_count<<<(N_INC + 255) / 256, 256, 0, stream>>>(he_node, he_edge, cnt_e, deg);
  k_scan<<<1, 1024, 0, stream>>>(cnt_e, e_start, N_EDGES);
  k_scan<<<1, 1024, 0, stream>>>(deg, n_start, N_NODES);
  k_fill<<<(N_INC + 255) / 256, 256, 0, stream>>>(he_node, he_edge, e_start, n_start,
                                                  cur_e, cur_n, e_idx, n_idx);
  k_gstart<<<(N_GRAPHS + 1 + 255) / 256, 256, 0, stream>>>(batch, gstart);
  // weight transposes
  k_transpose<<<(F_IN * HID + 255) / 256, 256, 0, stream>>>(w_lin, wlinT, F_IN, HID);
  k_transpose<<<(512 * HID + 255) / 256, 256, 0, stream>>>(w_causal, wcT, 512, HID);
  k_transpose<<<(HID * ODIM + 255) / 256, 256, 0, stream>>>(w_link, wlkT, HID, ODIM);

  // xh = x @ w_lin ; eattr ; eh = eattr @ w_lin
  k_gemm<<<dim3(1, N_NODES / 32), 256, 0, stream>>>(x, wlinT, xh, N_NODES, HID, F_IN,
                                                    nullptr, nullptr, 0, 0);
  k_eattr<<<N_EDGES / 4, 256, 0, stream>>>(x, he_node, e_start, e_idx, eattr);
  k_gemm<<<dim3(1, N_EDGES / 32), 256, 0, stream>>>(eattr, wlinT, eh, N_EDGES, HID, F_IN,
                                                    nullptr, nullptr, 0, 0);
  // separable attention logits + softmax
  k_dot<<<N_NODES / 4, 256, 0, stream>>>(xh, att, s_n, 0, N_NODES);
  k_dot<<<N_EDGES / 4, 256, 0, stream>>>(eh, att, s_e, 1, N_EDGES);
  k_logit<<<(N_INC + 255) / 256, 256, 0, stream>>>(he_node, he_edge, s_n, s_e, alpha);
  k_softmax<<<N_EDGES / 4, 256, 0, stream>>>(e_start, e_idx, alpha);
  // two-hop propagation
  k_out_e<<<N_EDGES / 4, 256, 0, stream>>>(xh, alpha, e_start, e_idx, he_node, out_e);
  k_out_n<<<N_NODES / 4, 256, 0, stream>>>(out_e, alpha, n_start, n_idx, he_edge, bias, xh);
  // pooling
  k_pool<<<N_GRAPHS, 256, 0, stream>>>(xh, gstart, pooled);

  // LSTM layer 1
  k_gemm<<<dim3(8, 512 / 32), 256, 0, stream>>>(pooled, w_ih0, xg1, 512, 2048, HID,
                                                b_ih0, b_hh0, 0, 0);
  k_lstm2<<<32, 256, 0, stream>>>(xg1, w_hh0, l1, hbuf, lcnt, 1, 32);
  // LSTM layer 2
  k_gemm<<<dim3(8, 512 / 32), 256, 0, stream>>>(l1, w_ih1, xg2, 512, 2048, 512,
                                                b_ih1, b_hh1, 0, 0);
  k_lstm2<<<32, 256, 0, stream>>>(xg2, w_hh1, l2, hbuf + 2 * 2 * 16 * 256, lcnt + 64, 16, 1);
  // heads
  k_gemm<<<dim3(1, 512 / 32), 256, 0, stream>>>(l2, wcT, causal, 512, HID, 512,
                                                b_causal, nullptr, 1, 0);
  k_gemm<<<dim3(1, 512 / 32), 256, 0, stream>>>(causal, wlkT, out, 512, ODIM, HID,
                                                b_link, nullptr, 2, 1);
  (void)in_sizes; (void)n_in; (void)out_size; (void)ws_size;
}

// Round 5
// 1886.574 us; speedup vs baseline: 1.4566x; 1.1455x over previous
//
#include <hip/hip_runtime.h>
#include <math.h>

#define N_NODES  100000
#define N_INC    400000
#define N_EDGES  20000
#define N_GRAPHS 512
#define F_IN     128
#define HID      256
#define RNN_H    256
#define ODIM     128

// ---------------- counting / CSR ----------------
__global__ void k_count(const int* __restrict__ he_node, const int* __restrict__ he_edge,
                        int* __restrict__ cnt_e, int* __restrict__ deg) {
  int i = blockIdx.x * 256 + threadIdx.x;
  if (i >= N_INC) return;
  atomicAdd(&cnt_e[he_edge[i]], 1);
  atomicAdd(&deg[he_node[i]], 1);
}

__global__ __launch_bounds__(1024)
void k_scan(const int* __restrict__ cnt, int* __restrict__ start, int n) {
  __shared__ int part[1024];
  int tid = threadIdx.x;
  int chunk = (n + 1023) / 1024;
  int lo = tid * chunk; if (lo > n) lo = n;
  int hi = lo + chunk;  if (hi > n) hi = n;
  int s = 0;
  for (int i = lo; i < hi; ++i) s += cnt[i];
  part[tid] = s;
  __syncthreads();
  for (int off = 1; off < 1024; off <<= 1) {
    int v = (tid >= off) ? part[tid - off] : 0;
    __syncthreads();
    part[tid] += v;
    __syncthreads();
  }
  int run = (tid == 0) ? 0 : part[tid - 1];
  for (int i = lo; i < hi; ++i) { start[i] = run; run += cnt[i]; }
  if (tid == 1023) start[n] = part[1023];
}

__global__ void k_fill(const int* __restrict__ he_node, const int* __restrict__ he_edge,
                       const int* __restrict__ e_start, const int* __restrict__ n_start,
                       int* __restrict__ cur_e, int* __restrict__ cur_n,
                       int* __restrict__ e_idx, int* __restrict__ n_idx) {
  int i = blockIdx.x * 256 + threadIdx.x;
  if (i >= N_INC) return;
  int e = he_edge[i]; int p = atomicAdd(&cur_e[e], 1); e_idx[e_start[e] + p] = i;
  int nn = he_node[i]; int q = atomicAdd(&cur_n[nn], 1); n_idx[n_start[nn] + q] = i;
}

__global__ void k_transpose(const float* __restrict__ in, float* __restrict__ out,
                            int rows, int cols) {
  int idx = blockIdx.x * 256 + threadIdx.x;
  if (idx >= rows * cols) return;
  int r = idx / cols, c = idx - r * cols;
  out[c * rows + r] = in[idx];
}

// ---------------- generic fp32 GEMM: C[M,N] = act(A[M,K] @ WT[N,K]^T + b1 + b2) ----------------
__global__ __launch_bounds__(256)
void k_gemm(const float* __restrict__ A, const float* __restrict__ WT,
            float* __restrict__ C, int M, int N, int K,
            const float* __restrict__ bias1, const float* __restrict__ bias2,
            int act, int remap) {
  __shared__ float As[32][132];
  int m0 = blockIdx.y * 32;
  int c  = blockIdx.x * 256 + threadIdx.x;
  float acc[32];
#pragma unroll
  for (int r = 0; r < 32; ++r) acc[r] = 0.f;
  for (int kc = 0; kc < K; kc += 128) {
    for (int it = threadIdx.x; it < 1024; it += 256) {
      int r = it >> 5, c4 = it & 31;
      float4 v = *(const float4*)&A[(size_t)(m0 + r) * K + kc + c4 * 4];
      *(float4*)&As[r][c4 * 4] = v;
    }
    __syncthreads();
    if (c < N) {
      const float4* w4p = (const float4*)&WT[(size_t)c * K + kc];
#pragma unroll 4
      for (int k4 = 0; k4 < 32; ++k4) {
        float4 w = w4p[k4];
#pragma unroll
        for (int r = 0; r < 32; ++r) {
          float4 a = *(const float4*)&As[r][k4 * 4];
          acc[r] += a.x * w.x + a.y * w.y + a.z * w.z + a.w * w.w;
        }
      }
    }
    __syncthreads();
  }
  if (c >= N) return;
  float b = (bias1 ? bias1[c] : 0.f) + (bias2 ? bias2[c] : 0.f);
  for (int r = 0; r < 32; ++r) {
    float v = acc[r] + b;
    if (act == 1) v = fmaxf(v, 0.f);
    else if (act == 2) v = 1.f / (1.f + expf(-v));
    int row = m0 + r;
    int orow = remap ? ((row & 15) * 32 + (row >> 4)) : row;
    C[(size_t)orow * N + c] = v;
  }
}

// ---------------- hyperedge mean of raw node features (wave per edge) ----------------
__global__ __launch_bounds__(256)
void k_eattr(const float* __restrict__ x, const int* __restrict__ he_node,
             const int* __restrict__ e_start, const int* __restrict__ e_idx,
             float* __restrict__ eattr) {
  int m = blockIdx.x * 4 + (threadIdx.x >> 6);
  if (m >= N_EDGES) return;
  int lane = threadIdx.x & 63;
  int c4 = lane & 31, jp = lane >> 5;
  int begin = e_start[m], end = e_start[m + 1];
  float4 acc = {0.f, 0.f, 0.f, 0.f};
  for (int j = begin + jp; j < end; j += 2) {
    float4 v = *(const float4*)&x[(size_t)he_node[e_idx[j]] * F_IN + c4 * 4];
    acc.x += v.x; acc.y += v.y; acc.z += v.z; acc.w += v.w;
  }
  acc.x += __shfl_xor(acc.x, 32); acc.y += __shfl_xor(acc.y, 32);
  acc.z += __shfl_xor(acc.z, 32); acc.w += __shfl_xor(acc.w, 32);
  if (jp == 0) {
    float inv = 1.f / fmaxf((float)(end - begin), 1.f);
    float4 o = {acc.x * inv, acc.y * inv, acc.z * inv, acc.w * inv};
    *(float4*)&eattr[(size_t)m * F_IN + c4 * 4] = o;
  }
}

// ---------------- separable attention: per-row dot with att half ----------------
__global__ __launch_bounds__(256)
void k_dot(const float* __restrict__ X, const float* __restrict__ att,
           float* __restrict__ s, int half, int nrows) {
  int row = blockIdx.x * 4 + (threadIdx.x >> 6);
  if (row >= nrows) return;
  int lane = threadIdx.x & 63;
  int h = lane >> 4;
  float4 v = *(const float4*)&X[(size_t)row * HID + lane * 4];
  float4 a = *(const float4*)&att[h * 128 + half * 64 + (lane & 15) * 4];
  float p = v.x * a.x + v.y * a.y + v.z * a.z + v.w * a.w;
  p += __shfl_xor(p, 1); p += __shfl_xor(p, 2);
  p += __shfl_xor(p, 4); p += __shfl_xor(p, 8);
  if ((lane & 15) == 0) s[(size_t)row * 4 + h] = p;
}

// ---------------- logits: gather s_n + s_e, leaky relu ----------------
__global__ void k_logit(const int* __restrict__ he_node, const int* __restrict__ he_edge,
                        const float* __restrict__ s_n, const float* __restrict__ s_e,
                        float* __restrict__ alpha) {
  int i = blockIdx.x * 256 + threadIdx.x;
  if (i >= N_INC) return;
  float4 a = *(const float4*)&s_n[(size_t)he_node[i] * 4];
  float4 b = *(const float4*)&s_e[(size_t)he_edge[i] * 4];
  float4 o;
  o.x = a.x + b.x; o.y = a.y + b.y; o.z = a.z + b.z; o.w = a.w + b.w;
  o.x = o.x > 0.f ? o.x : 0.2f * o.x;
  o.y = o.y > 0.f ? o.y : 0.2f * o.y;
  o.z = o.z > 0.f ? o.z : 0.2f * o.z;
  o.w = o.w > 0.f ? o.w : 0.2f * o.w;
  *(float4*)&alpha[(size_t)i * 4] = o;
}

// ---------------- per-hyperedge softmax (one wave per edge) ----------------
__global__ __launch_bounds__(256)
void k_softmax(const int* __restrict__ e_start, const int* __restrict__ e_idx,
               float* __restrict__ alpha) {
  int m = blockIdx.x * 4 + (threadIdx.x >> 6);
  if (m >= N_EDGES) return;
  int lane = threadIdx.x & 63;
  int begin = e_start[m], end = e_start[m + 1];
  int cnt = end - begin;
  if (cnt == 0) return;
  int nch = (cnt + 63) >> 6;
  float mx[4] = {-1e30f, -1e30f, -1e30f, -1e30f};
  for (int ch = 0; ch < nch; ++ch) {
    int j = begin + ch * 64 + lane;
    if (j < end) {
      float4 a = *(const float4*)&alpha[(size_t)e_idx[j] * 4];
      mx[0] = fmaxf(mx[0], a.x); mx[1] = fmaxf(mx[1], a.y);
      mx[2] = fmaxf(mx[2], a.z); mx[3] = fmaxf(mx[3], a.w);
    }
  }
#pragma unroll
  for (int h = 0; h < 4; ++h)
    for (int off = 32; off; off >>= 1) mx[h] = fmaxf(mx[h], __shfl_xor(mx[h], off));
  float s[4] = {0.f, 0.f, 0.f, 0.f};
  for (int ch = 0; ch < nch; ++ch) {
    int j = begin + ch * 64 + lane;
    if (j < end) {
      int i = e_idx[j];
      float4 a = *(const float4*)&alpha[(size_t)i * 4];
      a.x = expf(a.x - mx[0]); a.y = expf(a.y - mx[1]);
      a.z = expf(a.z - mx[2]); a.w = expf(a.w - mx[3]);
      *(float4*)&alpha[(size_t)i * 4] = a;
      s[0] += a.x; s[1] += a.y; s[2] += a.z; s[3] += a.w;
    }
  }
#pragma unroll
  for (int h = 0; h < 4; ++h) {
    for (int off = 32; off; off >>= 1) s[h] += __shfl_xor(s[h], off);
    s[h] = 1.f / fmaxf(s[h], 1e-16f);
  }
  for (int ch = 0; ch < nch; ++ch) {
    int j = begin + ch * 64 + lane;
    if (j < end) {
      int i = e_idx[j];
      float4 a = *(const float4*)&alpha[(size_t)i * 4];
      a.x *= s[0]; a.y *= s[1]; a.z *= s[2]; a.w *= s[3];
      *(float4*)&alpha[(size_t)i * 4] = a;
    }
  }
}

// ---------------- hop 1: node -> hyperedge (wave per edge) ----------------
__global__ __launch_bounds__(256)
void k_out_e(const float* __restrict__ xh, const float* __restrict__ alpha,
             const int* __restrict__ e_start, const int* __restrict__ e_idx,
             const int* __restrict__ he_node, float* __restrict__ out_e) {
  int m = blockIdx.x * 4 + (threadIdx.x >> 6);
  if (m >= N_EDGES) return;
  int lane = threadIdx.x & 63, h = lane >> 4;
  int begin = e_start[m], end = e_start[m + 1];
  float4 acc = {0.f, 0.f, 0.f, 0.f};
  for (int j = begin; j < end; ++j) {
    int i = e_idx[j];
    float a = alpha[(size_t)i * 4 + h];
    float4 v = *(const float4*)&xh[(size_t)he_node[i] * HID + lane * 4];
    acc.x += a * v.x; acc.y += a * v.y; acc.z += a * v.z; acc.w += a * v.w;
  }
  float bi = (end > begin) ? 1.f / (float)(end - begin) : 0.f;
  float4 o = {acc.x * bi, acc.y * bi, acc.z * bi, acc.w * bi};
  *(float4*)&out_e[(size_t)m * HID + lane * 4] = o;
}

// ---------------- hop 2: hyperedge -> node, + bias + relu (wave per node) ----------------
__global__ __launch_bounds__(256)
void k_out_n(const float* __restrict__ out_e, const float* __restrict__ alpha,
             const int* __restrict__ n_start, const int* __restrict__ n_idx,
             const int* __restrict__ he_edge, const float* __restrict__ bias,
             float* __restrict__ hout) {
  int n = blockIdx.x * 4 + (threadIdx.x >> 6);
  if (n >= N_NODES) return;
  int lane = threadIdx.x & 63, h = lane >> 4;
  int begin = n_start[n], end = n_start[n + 1];
  float4 acc = {0.f, 0.f, 0.f, 0.f};
  for (int j = begin; j < end; ++j) {
    int i = n_idx[j];
    float a = alpha[(size_t)i * 4 + h];
    float4 v = *(const float4*)&out_e[(size_t)he_edge[i] * HID + lane * 4];
    acc.x += a * v.x; acc.y += a * v.y; acc.z += a * v.z; acc.w += a * v.w;
  }
  float di = (end > begin) ? 1.f / (float)(end - begin) : 0.f;
  float4 bb = *(const float4*)&bias[lane * 4];
  float4 o;
  o.x = fmaxf(acc.x * di + bb.x, 0.f);
  o.y = fmaxf(acc.y * di + bb.y, 0.f);
  o.z = fmaxf(acc.z * di + bb.z, 0.f);
  o.w = fmaxf(acc.w * di + bb.w, 0.f);
  *(float4*)&hout[(size_t)n * HID + lane * 4] = o;
}

// ---------------- graph segment starts (batch is sorted) ----------------
__global__ void k_gstart(const int* __restrict__ batch, int* __restrict__ gs) {
  int g = blockIdx.x * 256 + threadIdx.x;
  if (g > N_GRAPHS) return;
  int lo = 0, hi = N_NODES;
  while (lo < hi) { int mid = (lo + hi) >> 1; if (batch[mid] < g) lo = mid + 1; else hi = mid; }
  gs[g] = lo;
}

__global__ __launch_bounds__(256)
void k_pool(const float* __restrict__ h, const int* __restrict__ gs,
            float* __restrict__ pooled) {
  __shared__ float4 part[4][64];
  int g = blockIdx.x, tid = threadIdx.x;
  int rs = tid >> 6, c4 = tid & 63;
  int begin = gs[g], end = gs[g + 1];
  float4 acc = {0.f, 0.f, 0.f, 0.f};
  for (int n = begin + rs; n < end; n += 4) {
    float4 v = *(const float4*)&h[(size_t)n * HID + c4 * 4];
    acc.x += v.x; acc.y += v.y; acc.z += v.z; acc.w += v.w;
  }
  part[rs][c4] = acc;
  __syncthreads();
  if (rs == 0) {
    float4 a = part[0][c4], b = part[1][c4], c = part[2][c4], d = part[3][c4];
    float inv = 1.f / fmaxf((float)(end - begin), 1.f);
    float4 o = {(a.x + b.x + c.x + d.x) * inv, (a.y + b.y + c.y + d.y) * inv,
                (a.z + b.z + c.z + d.z) * inv, (a.w + b.w + c.w + d.w) * inv};
    *(float4*)&pooled[(size_t)g * HID + c4 * 4] = o;
  }
}

// ---------------- BiLSTM recurrence: 32 blocks, fence-free coherent barrier ----------------
// h exchange per step is 16 KB; instead of agent fences (wbL2+inv, ~12us/step measured in r3),
// use per-access coherence: h stores = relaxed agent atomic (write-through sc0 sc1), readers
// stage hprev->LDS via sc0 sc1 loads (bypass stale L1/L2), counter = relaxed agent RMW.
// All 4 loads + the waitcnt live in ONE asm block (no tied operands - gfx950 limitation).
__global__ __launch_bounds__(256)
void k_lstm2(const float* __restrict__ xg, const float* __restrict__ w_hh,
             float* __restrict__ out, float* __restrict__ hbuf,
             int* __restrict__ lc, int rst, int rsb) {
  __shared__ float4 ws4[64][64];   // 64 KB weights
  __shared__ float4 hs[16 * 64];   // 16 KB staged hprev, col-swizzled
  const int dir = blockIdx.x >> 4, q = blockIdx.x & 15;
  const int tid = threadIdx.x;
  const int l = tid & 63, w = tid >> 6;
  const int ks = l & 3, rg = l >> 2;

  // stage w_hh rows (4 gates x 16 hid) with bank-balancing XOR swizzle
  for (int it = tid; it < 4096; it += 256) {
    int row = it >> 6, c4 = it & 63;         // row = g*16 + r
    int g = row >> 4, r = row & 15;
    float4 v = *(const float4*)&w_hh[((size_t)dir * 1024 + g * 256 + q * 16 + r) * 256 + c4 * 4];
    ws4[row][c4 ^ ((c4 >> 4) & 3) ^ (r & 7)] = v;
  }
  __syncthreads();

  float cst[4] = {0.f, 0.f, 0.f, 0.f};
  for (int t = 0; t < 32; ++t) {
    const int te = dir ? (31 - t) : t;
    // ---- stage hprev (global, coherent) -> LDS ----
    const float* hprev = hbuf + ((size_t)(t & 1) * 2 + dir) * 16 * 256;
    float4 hv0, hv1, hv2, hv3;
    {
      const float* a0 = hprev + (0 * 256 + tid) * 4;
      const float* a1 = hprev + (1 * 256 + tid) * 4;
      const float* a2 = hprev + (2 * 256 + tid) * 4;
      const float* a3 = hprev + (3 * 256 + tid) * 4;
      asm volatile(
        "global_load_dwordx4 %0, %4, off sc0 sc1\n"
        "global_load_dwordx4 %1, %5, off sc0 sc1\n"
        "global_load_dwordx4 %2, %6, off sc0 sc1\n"
        "global_load_dwordx4 %3, %7, off sc0 sc1\n"
        "s_waitcnt vmcnt(0)"
        : "=&v"(hv0), "=&v"(hv1), "=&v"(hv2), "=&v"(hv3)
        : "v"(a0), "v"(a1), "v"(a2), "v"(a3)
        : "memory");
    }
#pragma unroll
    for (int i = 0; i < 4; ++i) {
      int idx = i * 256 + tid;
      int b = idx >> 6, cc = idx & 63;
      float4 hv = (i == 0) ? hv0 : (i == 1) ? hv1 : (i == 2) ? hv2 : hv3;
      hs[b * 64 + (cc ^ ((cc >> 4) & 3))] = hv;
    }
    __syncthreads();

    // ---- gates = xg + hprev @ W^T ----
    float acc[4][4];
#pragma unroll
    for (int g = 0; g < 4; ++g)
#pragma unroll
      for (int lb = 0; lb < 4; ++lb) acc[g][lb] = 0.f;
#pragma unroll
    for (int j = 0; j < 16; ++j) {
      int col = ks * 16 + j;
      int u = col ^ ((col >> 4) & 3);
      float4 h4[4];
#pragma unroll
      for (int lb = 0; lb < 4; ++lb)
        h4[lb] = hs[(w * 4 + lb) * 64 + u];
      int csw = col ^ ks ^ (rg & 7);
#pragma unroll
      for (int g = 0; g < 4; ++g) {
        float4 wv = ws4[g * 16 + rg][csw];
#pragma unroll
        for (int lb = 0; lb < 4; ++lb)
          acc[g][lb] += wv.x * h4[lb].x + wv.y * h4[lb].y + wv.z * h4[lb].z + wv.w * h4[lb].w;
      }
    }
#pragma unroll
    for (int g = 0; g < 4; ++g)
#pragma unroll
      for (int lb = 0; lb < 4; ++lb) {
        float v = acc[g][lb];
        v += __shfl_xor(v, 1);
        v += __shfl_xor(v, 2);
        acc[g][lb] = v;
      }
    float hv[4];
#pragma unroll
    for (int lb = 0; lb < 4; ++lb) {
      int b = w * 4 + lb;
      const float* xp = &xg[(size_t)(b * rsb + te * rst) * 2048 + dir * 1024 + q * 16 + rg];
      float gi = acc[0][lb] + xp[0];
      float gf = acc[1][lb] + xp[256];
      float gg = acc[2][lb] + xp[512];
      float go = acc[3][lb] + xp[768];
      gi = 1.f / (1.f + expf(-gi));
      gf = 1.f / (1.f + expf(-gf));
      gg = tanhf(gg);
      go = 1.f / (1.f + expf(-go));
      cst[lb] = gf * cst[lb] + gi * gg;
      hv[lb] = go * tanhf(cst[lb]);
    }
    float* hnext = hbuf + ((size_t)((t + 1) & 1) * 2 + dir) * 16 * 256;
    if (ks == 0) {
#pragma unroll
      for (int lb = 0; lb < 4; ++lb) {
        int b = w * 4 + lb;
        __hip_atomic_store(&hnext[b * 256 + q * 16 + rg], hv[lb],
                           __ATOMIC_RELAXED, __HIP_MEMORY_SCOPE_AGENT);
        out[((size_t)te * 16 + b) * 512 + dir * 256 + q * 16 + rg] = hv[lb];
      }
    }
    if (t < 31) {
      __syncthreads();  // drains all threads' stores (vmcnt 0 before s_barrier)
      if (tid == 0) {
        __hip_atomic_fetch_add(&lc[dir * 32 + t], 1, __ATOMIC_RELAXED, __HIP_MEMORY_SCOPE_AGENT);
        while (__hip_atomic_load(&lc[dir * 32 + t], __ATOMIC_RELAXED, __HIP_MEMORY_SCOPE_AGENT) < 16)
          __builtin_amdgcn_s_sleep(1);
      }
      __syncthreads();
    } else {
      __syncthreads();
    }
  }
}

// ---------------- launch ----------------
extern "C" void kernel_launch(void* const* d_in, const int* in_sizes, int n_in,
                              void* d_out, int out_size, void* d_ws, size_t ws_size,
                              hipStream_t stream) {
  const float* x        = (const float*)d_in[0];
  const int*   he_node  = (const int*)d_in[1];
  const int*   he_edge  = (const int*)d_in[2];
  const int*   batch    = (const int*)d_in[3];
  const float* w_lin    = (const float*)d_in[4];
  const float* att      = (const float*)d_in[5];
  const float* bias     = (const float*)d_in[6];
  const float* w_ih0    = (const float*)d_in[7];
  const float* w_hh0    = (const float*)d_in[8];
  const float* b_ih0    = (const float*)d_in[9];
  const float* b_hh0    = (const float*)d_in[10];
  const float* w_ih1    = (const float*)d_in[11];
  const float* w_hh1    = (const float*)d_in[12];
  const float* b_ih1    = (const float*)d_in[13];
  const float* b_hh1    = (const float*)d_in[14];
  const float* w_causal = (const float*)d_in[15];
  const float* b_causal = (const float*)d_in[16];
  const float* w_link   = (const float*)d_in[17];
  const float* b_link   = (const float*)d_in[18];
  float* out = (float*)d_out;

  char* ws = (char*)d_ws;
  size_t off = 0;
  auto alloc = [&](size_t bytes) -> void* {
    void* p = ws + off;
    off = (off + bytes + 255) & ~(size_t)255;
    return p;
  };
  float* xh      = (float*)alloc((size_t)N_NODES * HID * 4);   // reused as h after out_n
  float* eattr   = (float*)alloc((size_t)N_EDGES * F_IN * 4);
  float* eh      = (float*)alloc((size_t)N_EDGES * HID * 4);
  float* alpha   = (float*)alloc((size_t)N_INC * 4 * 4);
  float* out_e   = (float*)alloc((size_t)N_EDGES * HID * 4);
  float* s_n     = (float*)alloc((size_t)N_NODES * 4 * 4);
  float* s_e     = (float*)alloc((size_t)N_EDGES * 4 * 4);
  int*   cnt_e   = (int*)alloc(N_EDGES * 4);
  int*   deg     = (int*)alloc(N_NODES * 4);
  int*   e_start = (int*)alloc((N_EDGES + 1) * 4);
  int*   n_start = (int*)alloc((N_NODES + 1) * 4);
  int*   cur_e   = (int*)alloc(N_EDGES * 4);
  int*   cur_n   = (int*)alloc(N_NODES * 4);
  int*   e_idx   = (int*)alloc(N_INC * 4);
  int*   n_idx   = (int*)alloc(N_INC * 4);
  int*   gstart  = (int*)alloc((N_GRAPHS + 1) * 4);
  float* pooled  = (float*)alloc((size_t)N_GRAPHS * HID * 4);
  float* wlinT   = (float*)alloc((size_t)HID * F_IN * 4);
  float* wcT     = (float*)alloc((size_t)HID * 512 * 4);
  float* wlkT    = (float*)alloc((size_t)ODIM * HID * 4);
  float* xg1     = (float*)alloc((size_t)512 * 2048 * 4);
  float* xg2     = (float*)alloc((size_t)512 * 2048 * 4);
  float* l1      = (float*)alloc((size_t)512 * 512 * 4);
  float* l2      = (float*)alloc((size_t)512 * 512 * 4);
  float* causal  = (float*)alloc((size_t)512 * HID * 4);
  float* hbuf    = (float*)alloc((size_t)2 * 2 * 2 * 16 * 256 * 4);  // [layer][slot][dir][b][256]
  int*   lcnt    = (int*)alloc(2 * 64 * 4);

  (void)hipMemsetAsync(cnt_e, 0, N_EDGES * 4, stream);
  (void)hipMemsetAsync(deg,   0, N_NODES * 4, stream);
  (void)hipMemsetAsync(cur_e, 0, N_EDGES * 4, stream);
  (void)hipMemsetAsync(cur_n, 0, N_NODES * 4, stream);
  (void)hipMemsetAsync(hbuf,  0, (size_t)2 * 2 * 2 * 16 * 256 * 4, stream);
  (void)hipMemsetAsync(lcnt,  0, 2 * 64 * 4, stream);

  // CSR build
  k_count<<<(N_INC + 255) / 256, 256, 0, stream>>>(he_node, he_edge, cnt_e, deg);
  k_scan<<<1, 1024, 0, stream>>>(cnt_e, e_start, N_EDGES);
  k_scan<<<1, 1024, 0, stream>>>(deg, n_start, N_NODES);
  k_fill<<<(N_INC + 255) / 256, 256, 0, stream>>>(he_node, he_edge, e_start, n_start,
                                                  cur_e, cur_n, e_idx, n_idx);
  k_gstart<<<(N_GRAPHS + 1 + 255) / 256, 256, 0, stream>>>(batch, gstart);
  // weight transposes
  k_transpose<<<(F_IN * HID + 255) / 256, 256, 0, stream>>>(w_lin, wlinT, F_IN, HID);
  k_transpose<<<(512 * HID + 255) / 256, 256, 0, stream>>>(w_causal, wcT, 512, HID);
  k_transpose<<<(HID * ODIM + 255) / 256, 256, 0, stream>>>(w_link, wlkT, HID, ODIM);

  // xh = x @ w_lin ; eattr ; eh = eattr @ w_lin
  k_gemm<<<dim3(1, N_NODES / 32), 256, 0, stream>>>(x, wlinT, xh, N_NODES, HID, F_IN,
                                                    nullptr, nullptr, 0, 0);
  k_eattr<<<N_EDGES / 4, 256, 0, stream>>>(x, he_node, e_start, e_idx, eattr);
  k_gemm<<<dim3(1, N_EDGES / 32), 256, 0, stream>>>(eattr, wlinT, eh, N_EDGES, HID, F_IN,
                                                    nullptr, nullptr, 0, 0);
  // separable attention logits + softmax
  k_dot<<<N_NODES / 4, 256, 0, stream>>>(xh, att, s_n, 0, N_NODES);
  k_dot<<<N_EDGES / 4, 256, 0, stream>>>(eh, att, s_e, 1, N_EDGES);
  k_logit<<<(N_INC + 255) / 256, 256, 0, stream>>>(he_node, he_edge, s_n, s_e, alpha);
  k_softmax<<<N_EDGES / 4, 256, 0, stream>>>(e_start, e_idx, alpha);
  // two-hop propagation
  k_out_e<<<N_EDGES / 4, 256, 0, stream>>>(xh, alpha, e_start, e_idx, he_node, out_e);
  k_out_n<<<N_NODES / 4, 256, 0, stream>>>(out_e, alpha, n_start, n_idx, he_edge, bias, xh);
  // pooling
  k_pool<<<N_GRAPHS, 256, 0, stream>>>(xh, gstart, pooled);

  // LSTM layer 1
  k_gemm<<<dim3(8, 512 / 32), 256, 0, stream>>>(pooled, w_ih0, xg1, 512, 2048, HID,
                                                b_ih0, b_hh0, 0, 0);
  k_lstm2<<<32, 256, 0, stream>>>(xg1, w_hh0, l1, hbuf, lcnt, 1, 32);
  // LSTM layer 2
  k_gemm<<<dim3(8, 512 / 32), 256, 0, stream>>>(l1, w_ih1, xg2, 512, 2048, 512,
                                                b_ih1, b_hh1, 0, 0);
  k_lstm2<<<32, 256, 0, stream>>>(xg2, w_hh1, l2, hbuf + 2 * 2 * 16 * 256, lcnt + 64, 16, 1);
  // heads
  k_gemm<<<dim3(1, 512 / 32), 256, 0, stream>>>(l2, wcT, causal, 512, HID, 512,
                                                b_causal, nullptr, 1, 0);
  k_gemm<<<dim3(1, 512 / 32), 256, 0, stream>>>(causal, wlkT, out, 512, ODIM, HID,
                                                b_link, nullptr, 2, 1);
  (void)in_sizes; (void)n_in; (void)out_size; (void)ws_size;
}

// Round 6
// 1523.486 us; speedup vs baseline: 1.8038x; 1.2383x over previous
//
#include <hip/hip_runtime.h>
#include <math.h>

#define N_NODES  100000
#define N_INC    400000
#define N_EDGES  20000
#define N_GRAPHS 512
#define F_IN     128
#define HID      256
#define RNN_H    256
#define ODIM     128

// ---------------- counting / CSR ----------------
__global__ void k_count(const int* __restrict__ he_node, const int* __restrict__ he_edge,
                        int* __restrict__ cnt_e, int* __restrict__ deg) {
  int i = blockIdx.x * 256 + threadIdx.x;
  if (i >= N_INC) return;
  atomicAdd(&cnt_e[he_edge[i]], 1);
  atomicAdd(&deg[he_node[i]], 1);
}

__global__ __launch_bounds__(1024)
void k_scan(const int* __restrict__ cnt, int* __restrict__ start, int n) {
  __shared__ int part[1024];
  int tid = threadIdx.x;
  int chunk = (n + 1023) / 1024;
  int lo = tid * chunk; if (lo > n) lo = n;
  int hi = lo + chunk;  if (hi > n) hi = n;
  int s = 0;
  for (int i = lo; i < hi; ++i) s += cnt[i];
  part[tid] = s;
  __syncthreads();
  for (int off = 1; off < 1024; off <<= 1) {
    int v = (tid >= off) ? part[tid - off] : 0;
    __syncthreads();
    part[tid] += v;
    __syncthreads();
  }
  int run = (tid == 0) ? 0 : part[tid - 1];
  for (int i = lo; i < hi; ++i) { start[i] = run; run += cnt[i]; }
  if (tid == 1023) start[n] = part[1023];
}

__global__ void k_fill(const int* __restrict__ he_node, const int* __restrict__ he_edge,
                       const int* __restrict__ e_start, const int* __restrict__ n_start,
                       int* __restrict__ cur_e, int* __restrict__ cur_n,
                       int* __restrict__ e_idx, int* __restrict__ n_idx) {
  int i = blockIdx.x * 256 + threadIdx.x;
  if (i >= N_INC) return;
  int e = he_edge[i]; int p = atomicAdd(&cur_e[e], 1); e_idx[e_start[e] + p] = i;
  int nn = he_node[i]; int q = atomicAdd(&cur_n[nn], 1); n_idx[n_start[nn] + q] = i;
}

__global__ void k_transpose(const float* __restrict__ in, float* __restrict__ out,
                            int rows, int cols) {
  int idx = blockIdx.x * 256 + threadIdx.x;
  if (idx >= rows * cols) return;
  int r = idx / cols, c = idx - r * cols;
  out[c * rows + r] = in[idx];
}

// ---------------- 2D register-blocked fp32 GEMM ----------------
// C[M,N] = act(A[M,K] @ WT[N,K]^T + b1 + b2). Tile TT x TT, 256 threads as 16x16,
// each thread TR x TR outputs (TR = TT/16). K chunked by 64. A,W tiles in LDS at
// [TT][64] with XOR swizzle (k4 ^= row>>3) -> <=2-way bank conflicts on reads.
// Requires: N % TT == 0, K % 64 == 0. M guarded.
template<int TT, int TR>
__global__ __launch_bounds__(256)
void k_gemm(const float* __restrict__ A, const float* __restrict__ WT,
            float* __restrict__ C, int M, int N, int K,
            const float* __restrict__ bias1, const float* __restrict__ bias2,
            int act, int remap) {
  __shared__ float As[TT][64];
  __shared__ float Ws[TT][64];
  const int m0 = blockIdx.y * TT, n0 = blockIdx.x * TT;
  const int tid = threadIdx.x;
  const int tc = tid & 15, tr = tid >> 4;
  float acc[TR][TR];
#pragma unroll
  for (int r = 0; r < TR; ++r)
#pragma unroll
    for (int c = 0; c < TR; ++c) acc[r][c] = 0.f;

  for (int kc = 0; kc < K; kc += 64) {
    for (int it = tid; it < TT * 16; it += 256) {
      int r = it >> 4, c4 = it & 15;
      int sw = ((c4 ^ (r >> 3)) & 15) << 2;
      int row = m0 + r;
      float4 v = {0.f, 0.f, 0.f, 0.f};
      if (row < M) v = *(const float4*)&A[(size_t)row * K + kc + c4 * 4];
      *(float4*)&As[r][sw] = v;
      float4 wv = *(const float4*)&WT[(size_t)(n0 + r) * K + kc + c4 * 4];
      *(float4*)&Ws[r][sw] = wv;
    }
    __syncthreads();
#pragma unroll 4
    for (int k4 = 0; k4 < 16; ++k4) {
      float4 wv[TR], av[TR];
#pragma unroll
      for (int c = 0; c < TR; ++c) {
        int rw = tc * TR + c;
        wv[c] = *(const float4*)&Ws[rw][((k4 ^ (rw >> 3)) & 15) << 2];
      }
#pragma unroll
      for (int r = 0; r < TR; ++r) {
        int ra = tr * TR + r;
        av[r] = *(const float4*)&As[ra][((k4 ^ (ra >> 3)) & 15) << 2];
      }
#pragma unroll
      for (int r = 0; r < TR; ++r)
#pragma unroll
        for (int c = 0; c < TR; ++c)
          acc[r][c] += av[r].x * wv[c].x + av[r].y * wv[c].y +
                       av[r].z * wv[c].z + av[r].w * wv[c].w;
    }
    __syncthreads();
  }

#pragma unroll
  for (int r = 0; r < TR; ++r) {
    int row = m0 + tr * TR + r;
    if (row >= M) continue;
    int orow = remap ? ((row & 15) * 32 + (row >> 4)) : row;
#pragma unroll
    for (int c4 = 0; c4 < TR; c4 += 4) {
      float4 o;
      float* op = &o.x;
#pragma unroll
      for (int c = 0; c < 4; ++c) {
        int col = n0 + tc * TR + c4 + c;
        float v = acc[r][c4 + c] +
                  (bias1 ? bias1[col] : 0.f) + (bias2 ? bias2[col] : 0.f);
        if (act == 1) v = fmaxf(v, 0.f);
        else if (act == 2) v = 1.f / (1.f + expf(-v));
        op[c] = v;
      }
      *(float4*)&C[(size_t)orow * N + n0 + tc * TR + c4] = o;
    }
  }
}

// ---------------- hyperedge mean of raw node features (wave per edge) ----------------
__global__ __launch_bounds__(256)
void k_eattr(const float* __restrict__ x, const int* __restrict__ he_node,
             const int* __restrict__ e_start, const int* __restrict__ e_idx,
             float* __restrict__ eattr) {
  int m = blockIdx.x * 4 + (threadIdx.x >> 6);
  if (m >= N_EDGES) return;
  int lane = threadIdx.x & 63;
  int c4 = lane & 31, jp = lane >> 5;
  int begin = e_start[m], end = e_start[m + 1];
  float4 acc = {0.f, 0.f, 0.f, 0.f};
  for (int j = begin + jp; j < end; j += 2) {
    float4 v = *(const float4*)&x[(size_t)he_node[e_idx[j]] * F_IN + c4 * 4];
    acc.x += v.x; acc.y += v.y; acc.z += v.z; acc.w += v.w;
  }
  acc.x += __shfl_xor(acc.x, 32); acc.y += __shfl_xor(acc.y, 32);
  acc.z += __shfl_xor(acc.z, 32); acc.w += __shfl_xor(acc.w, 32);
  if (jp == 0) {
    float inv = 1.f / fmaxf((float)(end - begin), 1.f);
    float4 o = {acc.x * inv, acc.y * inv, acc.z * inv, acc.w * inv};
    *(float4*)&eattr[(size_t)m * F_IN + c4 * 4] = o;
  }
}

// ---------------- separable attention: per-row dot with att half ----------------
__global__ __launch_bounds__(256)
void k_dot(const float* __restrict__ X, const float* __restrict__ att,
           float* __restrict__ s, int half, int nrows) {
  int row = blockIdx.x * 4 + (threadIdx.x >> 6);
  if (row >= nrows) return;
  int lane = threadIdx.x & 63;
  int h = lane >> 4;
  float4 v = *(const float4*)&X[(size_t)row * HID + lane * 4];
  float4 a = *(const float4*)&att[h * 128 + half * 64 + (lane & 15) * 4];
  float p = v.x * a.x + v.y * a.y + v.z * a.z + v.w * a.w;
  p += __shfl_xor(p, 1); p += __shfl_xor(p, 2);
  p += __shfl_xor(p, 4); p += __shfl_xor(p, 8);
  if ((lane & 15) == 0) s[(size_t)row * 4 + h] = p;
}

// ---------------- logits: gather s_n + s_e, leaky relu ----------------
__global__ void k_logit(const int* __restrict__ he_node, const int* __restrict__ he_edge,
                        const float* __restrict__ s_n, const float* __restrict__ s_e,
                        float* __restrict__ alpha) {
  int i = blockIdx.x * 256 + threadIdx.x;
  if (i >= N_INC) return;
  float4 a = *(const float4*)&s_n[(size_t)he_node[i] * 4];
  float4 b = *(const float4*)&s_e[(size_t)he_edge[i] * 4];
  float4 o;
  o.x = a.x + b.x; o.y = a.y + b.y; o.z = a.z + b.z; o.w = a.w + b.w;
  o.x = o.x > 0.f ? o.x : 0.2f * o.x;
  o.y = o.y > 0.f ? o.y : 0.2f * o.y;
  o.z = o.z > 0.f ? o.z : 0.2f * o.z;
  o.w = o.w > 0.f ? o.w : 0.2f * o.w;
  *(float4*)&alpha[(size_t)i * 4] = o;
}

// ---------------- per-hyperedge softmax (one wave per edge) ----------------
__global__ __launch_bounds__(256)
void k_softmax(const int* __restrict__ e_start, const int* __restrict__ e_idx,
               float* __restrict__ alpha) {
  int m = blockIdx.x * 4 + (threadIdx.x >> 6);
  if (m >= N_EDGES) return;
  int lane = threadIdx.x & 63;
  int begin = e_start[m], end = e_start[m + 1];
  int cnt = end - begin;
  if (cnt == 0) return;
  int nch = (cnt + 63) >> 6;
  float mx[4] = {-1e30f, -1e30f, -1e30f, -1e30f};
  for (int ch = 0; ch < nch; ++ch) {
    int j = begin + ch * 64 + lane;
    if (j < end) {
      float4 a = *(const float4*)&alpha[(size_t)e_idx[j] * 4];
      mx[0] = fmaxf(mx[0], a.x); mx[1] = fmaxf(mx[1], a.y);
      mx[2] = fmaxf(mx[2], a.z); mx[3] = fmaxf(mx[3], a.w);
    }
  }
#pragma unroll
  for (int h = 0; h < 4; ++h)
    for (int off = 32; off; off >>= 1) mx[h] = fmaxf(mx[h], __shfl_xor(mx[h], off));
  float s[4] = {0.f, 0.f, 0.f, 0.f};
  for (int ch = 0; ch < nch; ++ch) {
    int j = begin + ch * 64 + lane;
    if (j < end) {
      int i = e_idx[j];
      float4 a = *(const float4*)&alpha[(size_t)i * 4];
      a.x = expf(a.x - mx[0]); a.y = expf(a.y - mx[1]);
      a.z = expf(a.z - mx[2]); a.w = expf(a.w - mx[3]);
      *(float4*)&alpha[(size_t)i * 4] = a;
      s[0] += a.x; s[1] += a.y; s[2] += a.z; s[3] += a.w;
    }
  }
#pragma unroll
  for (int h = 0; h < 4; ++h) {
    for (int off = 32; off; off >>= 1) s[h] += __shfl_xor(s[h], off);
    s[h] = 1.f / fmaxf(s[h], 1e-16f);
  }
  for (int ch = 0; ch < nch; ++ch) {
    int j = begin + ch * 64 + lane;
    if (j < end) {
      int i = e_idx[j];
      float4 a = *(const float4*)&alpha[(size_t)i * 4];
      a.x *= s[0]; a.y *= s[1]; a.z *= s[2]; a.w *= s[3];
      *(float4*)&alpha[(size_t)i * 4] = a;
    }
  }
}

// ---------------- hop 1: node -> hyperedge (wave per edge) ----------------
__global__ __launch_bounds__(256)
void k_out_e(const float* __restrict__ xh, const float* __restrict__ alpha,
             const int* __restrict__ e_start, const int* __restrict__ e_idx,
             const int* __restrict__ he_node, float* __restrict__ out_e) {
  int m = blockIdx.x * 4 + (threadIdx.x >> 6);
  if (m >= N_EDGES) return;
  int lane = threadIdx.x & 63, h = lane >> 4;
  int begin = e_start[m], end = e_start[m + 1];
  float4 acc = {0.f, 0.f, 0.f, 0.f};
  for (int j = begin; j < end; ++j) {
    int i = e_idx[j];
    float a = alpha[(size_t)i * 4 + h];
    float4 v = *(const float4*)&xh[(size_t)he_node[i] * HID + lane * 4];
    acc.x += a * v.x; acc.y += a * v.y; acc.z += a * v.z; acc.w += a * v.w;
  }
  float bi = (end > begin) ? 1.f / (float)(end - begin) : 0.f;
  float4 o = {acc.x * bi, acc.y * bi, acc.z * bi, acc.w * bi};
  *(float4*)&out_e[(size_t)m * HID + lane * 4] = o;
}

// ---------------- hop 2: hyperedge -> node, + bias + relu (wave per node) ----------------
__global__ __launch_bounds__(256)
void k_out_n(const float* __restrict__ out_e, const float* __restrict__ alpha,
             const int* __restrict__ n_start, const int* __restrict__ n_idx,
             const int* __restrict__ he_edge, const float* __restrict__ bias,
             float* __restrict__ hout) {
  int n = blockIdx.x * 4 + (threadIdx.x >> 6);
  if (n >= N_NODES) return;
  int lane = threadIdx.x & 63, h = lane >> 4;
  int begin = n_start[n], end = n_start[n + 1];
  float4 acc = {0.f, 0.f, 0.f, 0.f};
  for (int j = begin; j < end; ++j) {
    int i = n_idx[j];
    float a = alpha[(size_t)i * 4 + h];
    float4 v = *(const float4*)&out_e[(size_t)he_edge[i] * HID + lane * 4];
    acc.x += a * v.x; acc.y += a * v.y; acc.z += a * v.z; acc.w += a * v.w;
  }
  float di = (end > begin) ? 1.f / (float)(end - begin) : 0.f;
  float4 bb = *(const float4*)&bias[lane * 4];
  float4 o;
  o.x = fmaxf(acc.x * di + bb.x, 0.f);
  o.y = fmaxf(acc.y * di + bb.y, 0.f);
  o.z = fmaxf(acc.z * di + bb.z, 0.f);
  o.w = fmaxf(acc.w * di + bb.w, 0.f);
  *(float4*)&hout[(size_t)n * HID + lane * 4] = o;
}

// ---------------- graph segment starts (batch is sorted) ----------------
__global__ void k_gstart(const int* __restrict__ batch, int* __restrict__ gs) {
  int g = blockIdx.x * 256 + threadIdx.x;
  if (g > N_GRAPHS) return;
  int lo = 0, hi = N_NODES;
  while (lo < hi) { int mid = (lo + hi) >> 1; if (batch[mid] < g) lo = mid + 1; else hi = mid; }
  gs[g] = lo;
}

__global__ __launch_bounds__(256)
void k_pool(const float* __restrict__ h, const int* __restrict__ gs,
            float* __restrict__ pooled) {
  __shared__ float4 part[4][64];
  int g = blockIdx.x, tid = threadIdx.x;
  int rs = tid >> 6, c4 = tid & 63;
  int begin = gs[g], end = gs[g + 1];
  float4 acc = {0.f, 0.f, 0.f, 0.f};
  for (int n = begin + rs; n < end; n += 4) {
    float4 v = *(const float4*)&h[(size_t)n * HID + c4 * 4];
    acc.x += v.x; acc.y += v.y; acc.z += v.z; acc.w += v.w;
  }
  part[rs][c4] = acc;
  __syncthreads();
  if (rs == 0) {
    float4 a = part[0][c4], b = part[1][c4], c = part[2][c4], d = part[3][c4];
    float inv = 1.f / fmaxf((float)(end - begin), 1.f);
    float4 o = {(a.x + b.x + c.x + d.x) * inv, (a.y + b.y + c.y + d.y) * inv,
                (a.z + b.z + c.z + d.z) * inv, (a.w + b.w + c.w + d.w) * inv};
    *(float4*)&pooled[(size_t)g * HID + c4 * 4] = o;
  }
}

// ---------------- BiLSTM recurrence: 32 blocks, fence-free coherent barrier ----------------
__global__ __launch_bounds__(256)
void k_lstm2(const float* __restrict__ xg, const float* __restrict__ w_hh,
             float* __restrict__ out, float* __restrict__ hbuf,
             int* __restrict__ lc, int rst, int rsb) {
  __shared__ float4 ws4[64][64];   // 64 KB weights
  __shared__ float4 hs[16 * 64];   // 16 KB staged hprev, col-swizzled
  const int dir = blockIdx.x >> 4, q = blockIdx.x & 15;
  const int tid = threadIdx.x;
  const int l = tid & 63, w = tid >> 6;
  const int ks = l & 3, rg = l >> 2;

  for (int it = tid; it < 4096; it += 256) {
    int row = it >> 6, c4 = it & 63;         // row = g*16 + r
    int g = row >> 4, r = row & 15;
    float4 v = *(const float4*)&w_hh[((size_t)dir * 1024 + g * 256 + q * 16 + r) * 256 + c4 * 4];
    ws4[row][c4 ^ ((c4 >> 4) & 3) ^ (r & 7)] = v;
  }
  __syncthreads();

  float cst[4] = {0.f, 0.f, 0.f, 0.f};
  for (int t = 0; t < 32; ++t) {
    const int te = dir ? (31 - t) : t;
    const float* hprev = hbuf + ((size_t)(t & 1) * 2 + dir) * 16 * 256;
    float4 hv0, hv1, hv2, hv3;
    {
      const float* a0 = hprev + (0 * 256 + tid) * 4;
      const float* a1 = hprev + (1 * 256 + tid) * 4;
      const float* a2 = hprev + (2 * 256 + tid) * 4;
      const float* a3 = hprev + (3 * 256 + tid) * 4;
      asm volatile(
        "global_load_dwordx4 %0, %4, off sc0 sc1\n"
        "global_load_dwordx4 %1, %5, off sc0 sc1\n"
        "global_load_dwordx4 %2, %6, off sc0 sc1\n"
        "global_load_dwordx4 %3, %7, off sc0 sc1\n"
        "s_waitcnt vmcnt(0)"
        : "=&v"(hv0), "=&v"(hv1), "=&v"(hv2), "=&v"(hv3)
        : "v"(a0), "v"(a1), "v"(a2), "v"(a3)
        : "memory");
    }
#pragma unroll
    for (int i = 0; i < 4; ++i) {
      int idx = i * 256 + tid;
      int b = idx >> 6, cc = idx & 63;
      float4 hv = (i == 0) ? hv0 : (i == 1) ? hv1 : (i == 2) ? hv2 : hv3;
      hs[b * 64 + (cc ^ ((cc >> 4) & 3))] = hv;
    }
    __syncthreads();

    float acc[4][4];
#pragma unroll
    for (int g = 0; g < 4; ++g)
#pragma unroll
      for (int lb = 0; lb < 4; ++lb) acc[g][lb] = 0.f;
#pragma unroll
    for (int j = 0; j < 16; ++j) {
      int col = ks * 16 + j;
      int u = col ^ ((col >> 4) & 3);
      float4 h4[4];
#pragma unroll
      for (int lb = 0; lb < 4; ++lb)
        h4[lb] = hs[(w * 4 + lb) * 64 + u];
      int csw = col ^ ks ^ (rg & 7);
#pragma unroll
      for (int g = 0; g < 4; ++g) {
        float4 wv = ws4[g * 16 + rg][csw];
#pragma unroll
        for (int lb = 0; lb < 4; ++lb)
          acc[g][lb] += wv.x * h4[lb].x + wv.y * h4[lb].y + wv.z * h4[lb].z + wv.w * h4[lb].w;
      }
    }
#pragma unroll
    for (int g = 0; g < 4; ++g)
#pragma unroll
      for (int lb = 0; lb < 4; ++lb) {
        float v = acc[g][lb];
        v += __shfl_xor(v, 1);
        v += __shfl_xor(v, 2);
        acc[g][lb] = v;
      }
    float hv[4];
#pragma unroll
    for (int lb = 0; lb < 4; ++lb) {
      int b = w * 4 + lb;
      const float* xp = &xg[(size_t)(b * rsb + te * rst) * 2048 + dir * 1024 + q * 16 + rg];
      float gi = acc[0][lb] + xp[0];
      float gf = acc[1][lb] + xp[256];
      float gg = acc[2][lb] + xp[512];
      float go = acc[3][lb] + xp[768];
      gi = 1.f / (1.f + expf(-gi));
      gf = 1.f / (1.f + expf(-gf));
      gg = tanhf(gg);
      go = 1.f / (1.f + expf(-go));
      cst[lb] = gf * cst[lb] + gi * gg;
      hv[lb] = go * tanhf(cst[lb]);
    }
    float* hnext = hbuf + ((size_t)((t + 1) & 1) * 2 + dir) * 16 * 256;
    if (ks == 0) {
#pragma unroll
      for (int lb = 0; lb < 4; ++lb) {
        int b = w * 4 + lb;
        __hip_atomic_store(&hnext[b * 256 + q * 16 + rg], hv[lb],
                           __ATOMIC_RELAXED, __HIP_MEMORY_SCOPE_AGENT);
        out[((size_t)te * 16 + b) * 512 + dir * 256 + q * 16 + rg] = hv[lb];
      }
    }
    if (t < 31) {
      __syncthreads();
      if (tid == 0) {
        __hip_atomic_fetch_add(&lc[dir * 32 + t], 1, __ATOMIC_RELAXED, __HIP_MEMORY_SCOPE_AGENT);
        while (__hip_atomic_load(&lc[dir * 32 + t], __ATOMIC_RELAXED, __HIP_MEMORY_SCOPE_AGENT) < 16)
          __builtin_amdgcn_s_sleep(1);
      }
      __syncthreads();
    } else {
      __syncthreads();
    }
  }
}

// ---------------- launch ----------------
extern "C" void kernel_launch(void* const* d_in, const int* in_sizes, int n_in,
                              void* d_out, int out_size, void* d_ws, size_t ws_size,
                              hipStream_t stream) {
  const float* x        = (const float*)d_in[0];
  const int*   he_node  = (const int*)d_in[1];
  const int*   he_edge  = (const int*)d_in[2];
  const int*   batch    = (const int*)d_in[3];
  const float* w_lin    = (const float*)d_in[4];
  const float* att      = (const float*)d_in[5];
  const float* bias     = (const float*)d_in[6];
  const float* w_ih0    = (const float*)d_in[7];
  const float* w_hh0    = (const float*)d_in[8];
  const float* b_ih0    = (const float*)d_in[9];
  const float* b_hh0    = (const float*)d_in[10];
  const float* w_ih1    = (const float*)d_in[11];
  const float* w_hh1    = (const float*)d_in[12];
  const float* b_ih1    = (const float*)d_in[13];
  const float* b_hh1    = (const float*)d_in[14];
  const float* w_causal = (const float*)d_in[15];
  const float* b_causal = (const float*)d_in[16];
  const float* w_link   = (const float*)d_in[17];
  const float* b_link   = (const float*)d_in[18];
  float* out = (float*)d_out;

  char* ws = (char*)d_ws;
  size_t off = 0;
  auto alloc = [&](size_t bytes) -> void* {
    void* p = ws + off;
    off = (off + bytes + 255) & ~(size_t)255;
    return p;
  };
  float* xh      = (float*)alloc((size_t)N_NODES * HID * 4);   // reused as h after out_n
  float* eattr   = (float*)alloc((size_t)N_EDGES * F_IN * 4);
  float* eh      = (float*)alloc((size_t)N_EDGES * HID * 4);
  float* alpha   = (float*)alloc((size_t)N_INC * 4 * 4);
  float* out_e   = (float*)alloc((size_t)N_EDGES * HID * 4);
  float* s_n     = (float*)alloc((size_t)N_NODES * 4 * 4);
  float* s_e     = (float*)alloc((size_t)N_EDGES * 4 * 4);
  int*   cnt_e   = (int*)alloc(N_EDGES * 4);
  int*   deg     = (int*)alloc(N_NODES * 4);
  int*   e_start = (int*)alloc((N_EDGES + 1) * 4);
  int*   n_start = (int*)alloc((N_NODES + 1) * 4);
  int*   cur_e   = (int*)alloc(N_EDGES * 4);
  int*   cur_n   = (int*)alloc(N_NODES * 4);
  int*   e_idx   = (int*)alloc(N_INC * 4);
  int*   n_idx   = (int*)alloc(N_INC * 4);
  int*   gstart  = (int*)alloc((N_GRAPHS + 1) * 4);
  float* pooled  = (float*)alloc((size_t)N_GRAPHS * HID * 4);
  float* wlinT   = (float*)alloc((size_t)HID * F_IN * 4);
  float* wcT     = (float*)alloc((size_t)HID * 512 * 4);
  float* wlkT    = (float*)alloc((size_t)ODIM * HID * 4);
  float* xg1     = (float*)alloc((size_t)512 * 2048 * 4);
  float* xg2     = (float*)alloc((size_t)512 * 2048 * 4);
  float* l1      = (float*)alloc((size_t)512 * 512 * 4);
  float* l2      = (float*)alloc((size_t)512 * 512 * 4);
  float* causal  = (float*)alloc((size_t)512 * HID * 4);
  float* hbuf    = (float*)alloc((size_t)2 * 2 * 2 * 16 * 256 * 4);  // [layer][slot][dir][b][256]
  int*   lcnt    = (int*)alloc(2 * 64 * 4);

  (void)hipMemsetAsync(cnt_e, 0, N_EDGES * 4, stream);
  (void)hipMemsetAsync(deg,   0, N_NODES * 4, stream);
  (void)hipMemsetAsync(cur_e, 0, N_EDGES * 4, stream);
  (void)hipMemsetAsync(cur_n, 0, N_NODES * 4, stream);
  (void)hipMemsetAsync(hbuf,  0, (size_t)2 * 2 * 2 * 16 * 256 * 4, stream);
  (void)hipMemsetAsync(lcnt,  0, 2 * 64 * 4, stream);

  // CSR build
  k_count<<<(N_INC + 255) / 256, 256, 0, stream>>>(he_node, he_edge, cnt_e, deg);
  k_scan<<<1, 1024, 0, stream>>>(cnt_e, e_start, N_EDGES);
  k_scan<<<1, 1024, 0, stream>>>(deg, n_start, N_NODES);
  k_fill<<<(N_INC + 255) / 256, 256, 0, stream>>>(he_node, he_edge, e_start, n_start,
                                                  cur_e, cur_n, e_idx, n_idx);
  k_gstart<<<(N_GRAPHS + 1 + 255) / 256, 256, 0, stream>>>(batch, gstart);
  // weight transposes
  k_transpose<<<(F_IN * HID + 255) / 256, 256, 0, stream>>>(w_lin, wlinT, F_IN, HID);
  k_transpose<<<(512 * HID + 255) / 256, 256, 0, stream>>>(w_causal, wcT, 512, HID);
  k_transpose<<<(HID * ODIM + 255) / 256, 256, 0, stream>>>(w_link, wlkT, HID, ODIM);

  // xh = x @ w_lin ; eattr ; eh = eattr @ w_lin
  k_gemm<128, 8><<<dim3(HID / 128, (N_NODES + 127) / 128), 256, 0, stream>>>(
      x, wlinT, xh, N_NODES, HID, F_IN, nullptr, nullptr, 0, 0);
  k_eattr<<<N_EDGES / 4, 256, 0, stream>>>(x, he_node, e_start, e_idx, eattr);
  k_gemm<128, 8><<<dim3(HID / 128, (N_EDGES + 127) / 128), 256, 0, stream>>>(
      eattr, wlinT, eh, N_EDGES, HID, F_IN, nullptr, nullptr, 0, 0);
  // separable attention logits + softmax
  k_dot<<<N_NODES / 4, 256, 0, stream>>>(xh, att, s_n, 0, N_NODES);
  k_dot<<<N_EDGES / 4, 256, 0, stream>>>(eh, att, s_e, 1, N_EDGES);
  k_logit<<<(N_INC + 255) / 256, 256, 0, stream>>>(he_node, he_edge, s_n, s_e, alpha);
  k_softmax<<<N_EDGES / 4, 256, 0, stream>>>(e_start, e_idx, alpha);
  // two-hop propagation
  k_out_e<<<N_EDGES / 4, 256, 0, stream>>>(xh, alpha, e_start, e_idx, he_node, out_e);
  k_out_n<<<N_NODES / 4, 256, 0, stream>>>(out_e, alpha, n_start, n_idx, he_edge, bias, xh);
  // pooling
  k_pool<<<N_GRAPHS, 256, 0, stream>>>(xh, gstart, pooled);

  // LSTM layer 1
  k_gemm<64, 4><<<dim3(2048 / 64, 512 / 64), 256, 0, stream>>>(
      pooled, w_ih0, xg1, 512, 2048, HID, b_ih0, b_hh0, 0, 0);
  k_lstm2<<<32, 256, 0, stream>>>(xg1, w_hh0, l1, hbuf, lcnt, 1, 32);
  // LSTM layer 2
  k_gemm<64, 4><<<dim3(2048 / 64, 512 / 64), 256, 0, stream>>>(
      l1, w_ih1, xg2, 512, 2048, 512, b_ih1, b_hh1, 0, 0);
  k_lstm2<<<32, 256, 0, stream>>>(xg2, w_hh1, l2, hbuf + 2 * 2 * 16 * 256, lcnt + 64, 16, 1);
  // heads
  k_gemm<64, 4><<<dim3(HID / 64, 512 / 64), 256, 0, stream>>>(
      l2, wcT, causal, 512, HID, 512, b_causal, nullptr, 1, 0);
  k_gemm<64, 4><<<dim3(ODIM / 64, 512 / 64), 256, 0, stream>>>(
      causal, wlkT, out, 512, ODIM, HID, b_link, nullptr, 2, 1);
  (void)in_sizes; (void)n_in; (void)out_size; (void)ws_size;
}

// Round 7
// 1452.428 us; speedup vs baseline: 1.8920x; 1.0489x over previous
//
#include <hip/hip_runtime.h>
#include <math.h>

#define N_NODES  100000
#define N_INC    400000
#define N_EDGES  20000
#define N_GRAPHS 512
#define F_IN     128
#define HID      256
#define RNN_H    256
#define ODIM     128

// ---------------- counting / CSR ----------------
__global__ void k_count(const int* __restrict__ he_node, const int* __restrict__ he_edge,
                        int* __restrict__ cnt_e, int* __restrict__ deg) {
  int i = blockIdx.x * 256 + threadIdx.x;
  if (i >= N_INC) return;
  atomicAdd(&cnt_e[he_edge[i]], 1);
  atomicAdd(&deg[he_node[i]], 1);
}

__global__ __launch_bounds__(1024)
void k_scan(const int* __restrict__ cnt, int* __restrict__ start, int n) {
  __shared__ int part[1024];
  int tid = threadIdx.x;
  int chunk = (n + 1023) / 1024;
  int lo = tid * chunk; if (lo > n) lo = n;
  int hi = lo + chunk;  if (hi > n) hi = n;
  int s = 0;
  for (int i = lo; i < hi; ++i) s += cnt[i];
  part[tid] = s;
  __syncthreads();
  for (int off = 1; off < 1024; off <<= 1) {
    int v = (tid >= off) ? part[tid - off] : 0;
    __syncthreads();
    part[tid] += v;
    __syncthreads();
  }
  int run = (tid == 0) ? 0 : part[tid - 1];
  for (int i = lo; i < hi; ++i) { start[i] = run; run += cnt[i]; }
  if (tid == 1023) start[n] = part[1023];
}

__global__ void k_fill(const int* __restrict__ he_node, const int* __restrict__ he_edge,
                       const int* __restrict__ e_start, const int* __restrict__ n_start,
                       int* __restrict__ cur_e, int* __restrict__ cur_n,
                       int* __restrict__ e_idx, int* __restrict__ n_idx) {
  int i = blockIdx.x * 256 + threadIdx.x;
  if (i >= N_INC) return;
  int e = he_edge[i]; int p = atomicAdd(&cur_e[e], 1); e_idx[e_start[e] + p] = i;
  int nn = he_node[i]; int q = atomicAdd(&cur_n[nn], 1); n_idx[n_start[nn] + q] = i;
}

__global__ void k_transpose(const float* __restrict__ in, float* __restrict__ out,
                            int rows, int cols) {
  int idx = blockIdx.x * 256 + threadIdx.x;
  if (idx >= rows * cols) return;
  int r = idx / cols, c = idx - r * cols;
  out[c * rows + r] = in[idx];
}

// ---------------- 2D register-blocked fp32 GEMM ----------------
template<int TT, int TR>
__global__ __launch_bounds__(256)
void k_gemm(const float* __restrict__ A, const float* __restrict__ WT,
            float* __restrict__ C, int M, int N, int K,
            const float* __restrict__ bias1, const float* __restrict__ bias2,
            int act, int remap) {
  __shared__ float As[TT][64];
  __shared__ float Ws[TT][64];
  const int m0 = blockIdx.y * TT, n0 = blockIdx.x * TT;
  const int tid = threadIdx.x;
  const int tc = tid & 15, tr = tid >> 4;
  float acc[TR][TR];
#pragma unroll
  for (int r = 0; r < TR; ++r)
#pragma unroll
    for (int c = 0; c < TR; ++c) acc[r][c] = 0.f;

  for (int kc = 0; kc < K; kc += 64) {
    for (int it = tid; it < TT * 16; it += 256) {
      int r = it >> 4, c4 = it & 15;
      int sw = ((c4 ^ (r >> 3)) & 15) << 2;
      int row = m0 + r;
      float4 v = {0.f, 0.f, 0.f, 0.f};
      if (row < M) v = *(const float4*)&A[(size_t)row * K + kc + c4 * 4];
      *(float4*)&As[r][sw] = v;
      float4 wv = *(const float4*)&WT[(size_t)(n0 + r) * K + kc + c4 * 4];
      *(float4*)&Ws[r][sw] = wv;
    }
    __syncthreads();
#pragma unroll 4
    for (int k4 = 0; k4 < 16; ++k4) {
      float4 wv[TR], av[TR];
#pragma unroll
      for (int c = 0; c < TR; ++c) {
        int rw = tc * TR + c;
        wv[c] = *(const float4*)&Ws[rw][((k4 ^ (rw >> 3)) & 15) << 2];
      }
#pragma unroll
      for (int r = 0; r < TR; ++r) {
        int ra = tr * TR + r;
        av[r] = *(const float4*)&As[ra][((k4 ^ (ra >> 3)) & 15) << 2];
      }
#pragma unroll
      for (int r = 0; r < TR; ++r)
#pragma unroll
        for (int c = 0; c < TR; ++c)
          acc[r][c] += av[r].x * wv[c].x + av[r].y * wv[c].y +
                       av[r].z * wv[c].z + av[r].w * wv[c].w;
    }
    __syncthreads();
  }

#pragma unroll
  for (int r = 0; r < TR; ++r) {
    int row = m0 + tr * TR + r;
    if (row >= M) continue;
    int orow = remap ? ((row & 15) * 32 + (row >> 4)) : row;
#pragma unroll
    for (int c4 = 0; c4 < TR; c4 += 4) {
      float4 o;
      float* op = &o.x;
#pragma unroll
      for (int c = 0; c < 4; ++c) {
        int col = n0 + tc * TR + c4 + c;
        float v = acc[r][c4 + c] +
                  (bias1 ? bias1[col] : 0.f) + (bias2 ? bias2[col] : 0.f);
        if (act == 1) v = fmaxf(v, 0.f);
        else if (act == 2) v = 1.f / (1.f + expf(-v));
        op[c] = v;
      }
      *(float4*)&C[(size_t)orow * N + n0 + tc * TR + c4] = o;
    }
  }
}

// ---------------- hyperedge mean of raw node features (wave per edge) ----------------
__global__ __launch_bounds__(256)
void k_eattr(const float* __restrict__ x, const int* __restrict__ he_node,
             const int* __restrict__ e_start, const int* __restrict__ e_idx,
             float* __restrict__ eattr) {
  int m = blockIdx.x * 4 + (threadIdx.x >> 6);
  if (m >= N_EDGES) return;
  int lane = threadIdx.x & 63;
  int c4 = lane & 31, jp = lane >> 5;
  int begin = e_start[m], end = e_start[m + 1];
  float4 acc = {0.f, 0.f, 0.f, 0.f};
  for (int j = begin + jp; j < end; j += 2) {
    float4 v = *(const float4*)&x[(size_t)he_node[e_idx[j]] * F_IN + c4 * 4];
    acc.x += v.x; acc.y += v.y; acc.z += v.z; acc.w += v.w;
  }
  acc.x += __shfl_xor(acc.x, 32); acc.y += __shfl_xor(acc.y, 32);
  acc.z += __shfl_xor(acc.z, 32); acc.w += __shfl_xor(acc.w, 32);
  if (jp == 0) {
    float inv = 1.f / fmaxf((float)(end - begin), 1.f);
    float4 o = {acc.x * inv, acc.y * inv, acc.z * inv, acc.w * inv};
    *(float4*)&eattr[(size_t)m * F_IN + c4 * 4] = o;
  }
}

// ---------------- separable attention: per-row dot with att half ----------------
__global__ __launch_bounds__(256)
void k_dot(const float* __restrict__ X, const float* __restrict__ att,
           float* __restrict__ s, int half, int nrows) {
  int row = blockIdx.x * 4 + (threadIdx.x >> 6);
  if (row >= nrows) return;
  int lane = threadIdx.x & 63;
  int h = lane >> 4;
  float4 v = *(const float4*)&X[(size_t)row * HID + lane * 4];
  float4 a = *(const float4*)&att[h * 128 + half * 64 + (lane & 15) * 4];
  float p = v.x * a.x + v.y * a.y + v.z * a.z + v.w * a.w;
  p += __shfl_xor(p, 1); p += __shfl_xor(p, 2);
  p += __shfl_xor(p, 4); p += __shfl_xor(p, 8);
  if ((lane & 15) == 0) s[(size_t)row * 4 + h] = p;
}

// ---------------- logits: gather s_n + s_e, leaky relu ----------------
__global__ void k_logit(const int* __restrict__ he_node, const int* __restrict__ he_edge,
                        const float* __restrict__ s_n, const float* __restrict__ s_e,
                        float* __restrict__ alpha) {
  int i = blockIdx.x * 256 + threadIdx.x;
  if (i >= N_INC) return;
  float4 a = *(const float4*)&s_n[(size_t)he_node[i] * 4];
  float4 b = *(const float4*)&s_e[(size_t)he_edge[i] * 4];
  float4 o;
  o.x = a.x + b.x; o.y = a.y + b.y; o.z = a.z + b.z; o.w = a.w + b.w;
  o.x = o.x > 0.f ? o.x : 0.2f * o.x;
  o.y = o.y > 0.f ? o.y : 0.2f * o.y;
  o.z = o.z > 0.f ? o.z : 0.2f * o.z;
  o.w = o.w > 0.f ? o.w : 0.2f * o.w;
  *(float4*)&alpha[(size_t)i * 4] = o;
}

// ---------------- per-hyperedge softmax (one wave per edge) ----------------
__global__ __launch_bounds__(256)
void k_softmax(const int* __restrict__ e_start, const int* __restrict__ e_idx,
               float* __restrict__ alpha) {
  int m = blockIdx.x * 4 + (threadIdx.x >> 6);
  if (m >= N_EDGES) return;
  int lane = threadIdx.x & 63;
  int begin = e_start[m], end = e_start[m + 1];
  int cnt = end - begin;
  if (cnt == 0) return;
  int nch = (cnt + 63) >> 6;
  float mx[4] = {-1e30f, -1e30f, -1e30f, -1e30f};
  for (int ch = 0; ch < nch; ++ch) {
    int j = begin + ch * 64 + lane;
    if (j < end) {
      float4 a = *(const float4*)&alpha[(size_t)e_idx[j] * 4];
      mx[0] = fmaxf(mx[0], a.x); mx[1] = fmaxf(mx[1], a.y);
      mx[2] = fmaxf(mx[2], a.z); mx[3] = fmaxf(mx[3], a.w);
    }
  }
#pragma unroll
  for (int h = 0; h < 4; ++h)
    for (int off = 32; off; off >>= 1) mx[h] = fmaxf(mx[h], __shfl_xor(mx[h], off));
  float s[4] = {0.f, 0.f, 0.f, 0.f};
  for (int ch = 0; ch < nch; ++ch) {
    int j = begin + ch * 64 + lane;
    if (j < end) {
      int i = e_idx[j];
      float4 a = *(const float4*)&alpha[(size_t)i * 4];
      a.x = expf(a.x - mx[0]); a.y = expf(a.y - mx[1]);
      a.z = expf(a.z - mx[2]); a.w = expf(a.w - mx[3]);
      *(float4*)&alpha[(size_t)i * 4] = a;
      s[0] += a.x; s[1] += a.y; s[2] += a.z; s[3] += a.w;
    }
  }
#pragma unroll
  for (int h = 0; h < 4; ++h) {
    for (int off = 32; off; off >>= 1) s[h] += __shfl_xor(s[h], off);
    s[h] = 1.f / fmaxf(s[h], 1e-16f);
  }
  for (int ch = 0; ch < nch; ++ch) {
    int j = begin + ch * 64 + lane;
    if (j < end) {
      int i = e_idx[j];
      float4 a = *(const float4*)&alpha[(size_t)i * 4];
      a.x *= s[0]; a.y *= s[1]; a.z *= s[2]; a.w *= s[3];
      *(float4*)&alpha[(size_t)i * 4] = a;
    }
  }
}

// ---------------- hop 1: node -> hyperedge (wave per edge) ----------------
__global__ __launch_bounds__(256)
void k_out_e(const float* __restrict__ xh, const float* __restrict__ alpha,
             const int* __restrict__ e_start, const int* __restrict__ e_idx,
             const int* __restrict__ he_node, float* __restrict__ out_e) {
  int m = blockIdx.x * 4 + (threadIdx.x >> 6);
  if (m >= N_EDGES) return;
  int lane = threadIdx.x & 63, h = lane >> 4;
  int begin = e_start[m], end = e_start[m + 1];
  float4 acc = {0.f, 0.f, 0.f, 0.f};
  for (int j = begin; j < end; ++j) {
    int i = e_idx[j];
    float a = alpha[(size_t)i * 4 + h];
    float4 v = *(const float4*)&xh[(size_t)he_node[i] * HID + lane * 4];
    acc.x += a * v.x; acc.y += a * v.y; acc.z += a * v.z; acc.w += a * v.w;
  }
  float bi = (end > begin) ? 1.f / (float)(end - begin) : 0.f;
  float4 o = {acc.x * bi, acc.y * bi, acc.z * bi, acc.w * bi};
  *(float4*)&out_e[(size_t)m * HID + lane * 4] = o;
}

// ---------------- hop 2: hyperedge -> node, + bias + relu (wave per node) ----------------
__global__ __launch_bounds__(256)
void k_out_n(const float* __restrict__ out_e, const float* __restrict__ alpha,
             const int* __restrict__ n_start, const int* __restrict__ n_idx,
             const int* __restrict__ he_edge, const float* __restrict__ bias,
             float* __restrict__ hout) {
  int n = blockIdx.x * 4 + (threadIdx.x >> 6);
  if (n >= N_NODES) return;
  int lane = threadIdx.x & 63, h = lane >> 4;
  int begin = n_start[n], end = n_start[n + 1];
  float4 acc = {0.f, 0.f, 0.f, 0.f};
  for (int j = begin; j < end; ++j) {
    int i = n_idx[j];
    float a = alpha[(size_t)i * 4 + h];
    float4 v = *(const float4*)&out_e[(size_t)he_edge[i] * HID + lane * 4];
    acc.x += a * v.x; acc.y += a * v.y; acc.z += a * v.z; acc.w += a * v.w;
  }
  float di = (end > begin) ? 1.f / (float)(end - begin) : 0.f;
  float4 bb = *(const float4*)&bias[lane * 4];
  float4 o;
  o.x = fmaxf(acc.x * di + bb.x, 0.f);
  o.y = fmaxf(acc.y * di + bb.y, 0.f);
  o.z = fmaxf(acc.z * di + bb.z, 0.f);
  o.w = fmaxf(acc.w * di + bb.w, 0.f);
  *(float4*)&hout[(size_t)n * HID + lane * 4] = o;
}

// ---------------- graph segment starts (batch is sorted) ----------------
__global__ void k_gstart(const int* __restrict__ batch, int* __restrict__ gs) {
  int g = blockIdx.x * 256 + threadIdx.x;
  if (g > N_GRAPHS) return;
  int lo = 0, hi = N_NODES;
  while (lo < hi) { int mid = (lo + hi) >> 1; if (batch[mid] < g) lo = mid + 1; else hi = mid; }
  gs[g] = lo;
}

__global__ __launch_bounds__(256)
void k_pool(const float* __restrict__ h, const int* __restrict__ gs,
            float* __restrict__ pooled) {
  __shared__ float4 part[4][64];
  int g = blockIdx.x, tid = threadIdx.x;
  int rs = tid >> 6, c4 = tid & 63;
  int begin = gs[g], end = gs[g + 1];
  float4 acc = {0.f, 0.f, 0.f, 0.f};
  for (int n = begin + rs; n < end; n += 4) {
    float4 v = *(const float4*)&h[(size_t)n * HID + c4 * 4];
    acc.x += v.x; acc.y += v.y; acc.z += v.z; acc.w += v.w;
  }
  part[rs][c4] = acc;
  __syncthreads();
  if (rs == 0) {
    float4 a = part[0][c4], b = part[1][c4], c = part[2][c4], d = part[3][c4];
    float inv = 1.f / fmaxf((float)(end - begin), 1.f);
    float4 o = {(a.x + b.x + c.x + d.x) * inv, (a.y + b.y + c.y + d.y) * inv,
                (a.z + b.z + c.z + d.z) * inv, (a.w + b.w + c.w + d.w) * inv};
    *(float4*)&pooled[(size_t)g * HID + c4 * 4] = o;
  }
}

// ---------------- BiLSTM recurrence: 32 blocks, stamp barrier (no RMW contention) ----------------
// Per-block stamps stamp[dir*16+q] = t+1 after drain; all waves poll 16 stamps directly
// (lanes 0-15) and proceed. xg gate slice prefetched into registers before the poll so its
// memory latency overlaps the wait. h exchange via sc0/sc1 coherent loads/stores as before.
__global__ __launch_bounds__(256)
void k_lstm2(const float* __restrict__ xg, const float* __restrict__ w_hh,
             float* __restrict__ out, float* __restrict__ hbuf,
             int* __restrict__ stamp, int rst, int rsb) {
  __shared__ float4 ws4[64][64];   // 64 KB weights
  __shared__ float4 hs[16 * 64];   // 16 KB staged hprev, col-swizzled
  const int dir = blockIdx.x >> 4, q = blockIdx.x & 15;
  const int tid = threadIdx.x;
  const int l = tid & 63, w = tid >> 6;
  const int ks = l & 3, rg = l >> 2;

  for (int it = tid; it < 4096; it += 256) {
    int row = it >> 6, c4 = it & 63;         // row = g*16 + r
    int g = row >> 4, r = row & 15;
    float4 v = *(const float4*)&w_hh[((size_t)dir * 1024 + g * 256 + q * 16 + r) * 256 + c4 * 4];
    ws4[row][c4 ^ ((c4 >> 4) & 3) ^ (r & 7)] = v;
  }
  __syncthreads();

  float cst[4] = {0.f, 0.f, 0.f, 0.f};
  for (int t = 0; t < 32; ++t) {
    const int te = dir ? (31 - t) : t;
    // ---- prefetch xg gate slice (independent of the barrier) ----
    float xr[4][4];
#pragma unroll
    for (int lb = 0; lb < 4; ++lb) {
      const float* xp = &xg[(size_t)((w * 4 + lb) * rsb + te * rst) * 2048 + dir * 1024 + q * 16 + rg];
      xr[0][lb] = xp[0];
      xr[1][lb] = xp[256];
      xr[2][lb] = xp[512];
      xr[3][lb] = xp[768];
    }
    // ---- wait for all 16 producer chunks of h(t) ----
    if (t > 0) {
      for (;;) {
        int sv = t;
        if (l < 16)
          sv = __hip_atomic_load(&stamp[dir * 16 + l], __ATOMIC_RELAXED, __HIP_MEMORY_SCOPE_AGENT);
        if (__all(sv >= t)) break;
        __builtin_amdgcn_s_sleep(1);
      }
    }
    // ---- stage h(t) (global, coherent) -> LDS ----
    const float* hprev = hbuf + ((size_t)(t & 1) * 2 + dir) * 16 * 256;
    float4 hv0, hv1, hv2, hv3;
    {
      const float* a0 = hprev + (0 * 256 + tid) * 4;
      const float* a1 = hprev + (1 * 256 + tid) * 4;
      const float* a2 = hprev + (2 * 256 + tid) * 4;
      const float* a3 = hprev + (3 * 256 + tid) * 4;
      asm volatile(
        "global_load_dwordx4 %0, %4, off sc0 sc1\n"
        "global_load_dwordx4 %1, %5, off sc0 sc1\n"
        "global_load_dwordx4 %2, %6, off sc0 sc1\n"
        "global_load_dwordx4 %3, %7, off sc0 sc1\n"
        "s_waitcnt vmcnt(0)"
        : "=&v"(hv0), "=&v"(hv1), "=&v"(hv2), "=&v"(hv3)
        : "v"(a0), "v"(a1), "v"(a2), "v"(a3)
        : "memory");
    }
#pragma unroll
    for (int i = 0; i < 4; ++i) {
      int idx = i * 256 + tid;
      int b = idx >> 6, cc = idx & 63;
      float4 hv = (i == 0) ? hv0 : (i == 1) ? hv1 : (i == 2) ? hv2 : hv3;
      hs[b * 64 + (cc ^ ((cc >> 4) & 3))] = hv;
    }
    __syncthreads();

    // ---- gates = xg + hprev @ W^T ----
    float acc[4][4];
#pragma unroll
    for (int g = 0; g < 4; ++g)
#pragma unroll
      for (int lb = 0; lb < 4; ++lb) acc[g][lb] = 0.f;
#pragma unroll
    for (int j = 0; j < 16; ++j) {
      int col = ks * 16 + j;
      int u = col ^ ((col >> 4) & 3);
      float4 h4[4];
#pragma unroll
      for (int lb = 0; lb < 4; ++lb)
        h4[lb] = hs[(w * 4 + lb) * 64 + u];
      int csw = col ^ ks ^ (rg & 7);
#pragma unroll
      for (int g = 0; g < 4; ++g) {
        float4 wv = ws4[g * 16 + rg][csw];
#pragma unroll
        for (int lb = 0; lb < 4; ++lb)
          acc[g][lb] += wv.x * h4[lb].x + wv.y * h4[lb].y + wv.z * h4[lb].z + wv.w * h4[lb].w;
      }
    }
#pragma unroll
    for (int g = 0; g < 4; ++g)
#pragma unroll
      for (int lb = 0; lb < 4; ++lb) {
        float v = acc[g][lb];
        v += __shfl_xor(v, 1);
        v += __shfl_xor(v, 2);
        acc[g][lb] = v;
      }
    float hv[4];
#pragma unroll
    for (int lb = 0; lb < 4; ++lb) {
      float gi = acc[0][lb] + xr[0][lb];
      float gf = acc[1][lb] + xr[1][lb];
      float gg = acc[2][lb] + xr[2][lb];
      float go = acc[3][lb] + xr[3][lb];
      gi = 1.f / (1.f + expf(-gi));
      gf = 1.f / (1.f + expf(-gf));
      gg = tanhf(gg);
      go = 1.f / (1.f + expf(-go));
      cst[lb] = gf * cst[lb] + gi * gg;
      hv[lb] = go * tanhf(cst[lb]);
    }
    float* hnext = hbuf + ((size_t)((t + 1) & 1) * 2 + dir) * 16 * 256;
    if (ks == 0) {
#pragma unroll
      for (int lb = 0; lb < 4; ++lb) {
        int b = w * 4 + lb;
        __hip_atomic_store(&hnext[b * 256 + q * 16 + rg], hv[lb],
                           __ATOMIC_RELAXED, __HIP_MEMORY_SCOPE_AGENT);
        out[((size_t)te * 16 + b) * 512 + dir * 256 + q * 16 + rg] = hv[lb];
      }
    }
    if (t < 31) {
      __syncthreads();  // all waves drain vmcnt (stores visible) before stamping
      if (tid == 0)
        __hip_atomic_store(&stamp[dir * 16 + q], t + 1,
                           __ATOMIC_RELAXED, __HIP_MEMORY_SCOPE_AGENT);
    }
  }
}

// ---------------- launch ----------------
extern "C" void kernel_launch(void* const* d_in, const int* in_sizes, int n_in,
                              void* d_out, int out_size, void* d_ws, size_t ws_size,
                              hipStream_t stream) {
  const float* x        = (const float*)d_in[0];
  const int*   he_node  = (const int*)d_in[1];
  const int*   he_edge  = (const int*)d_in[2];
  const int*   batch    = (const int*)d_in[3];
  const float* w_lin    = (const float*)d_in[4];
  const float* att      = (const float*)d_in[5];
  const float* bias     = (const float*)d_in[6];
  const float* w_ih0    = (const float*)d_in[7];
  const float* w_hh0    = (const float*)d_in[8];
  const float* b_ih0    = (const float*)d_in[9];
  const float* b_hh0    = (const float*)d_in[10];
  const float* w_ih1    = (const float*)d_in[11];
  const float* w_hh1    = (const float*)d_in[12];
  const float* b_ih1    = (const float*)d_in[13];
  const float* b_hh1    = (const float*)d_in[14];
  const float* w_causal = (const float*)d_in[15];
  const float* b_causal = (const float*)d_in[16];
  const float* w_link   = (const float*)d_in[17];
  const float* b_link   = (const float*)d_in[18];
  float* out = (float*)d_out;

  char* ws = (char*)d_ws;
  size_t off = 0;
  auto alloc = [&](size_t bytes) -> void* {
    void* p = ws + off;
    off = (off + bytes + 255) & ~(size_t)255;
    return p;
  };
  float* xh      = (float*)alloc((size_t)N_NODES * HID * 4);   // reused as h after out_n
  float* eattr   = (float*)alloc((size_t)N_EDGES * F_IN * 4);
  float* eh      = (float*)alloc((size_t)N_EDGES * HID * 4);
  float* alpha   = (float*)alloc((size_t)N_INC * 4 * 4);
  float* out_e   = (float*)alloc((size_t)N_EDGES * HID * 4);
  float* s_n     = (float*)alloc((size_t)N_NODES * 4 * 4);
  float* s_e     = (float*)alloc((size_t)N_EDGES * 4 * 4);
  int*   cnt_e   = (int*)alloc(N_EDGES * 4);
  int*   deg     = (int*)alloc(N_NODES * 4);
  int*   e_start = (int*)alloc((N_EDGES + 1) * 4);
  int*   n_start = (int*)alloc((N_NODES + 1) * 4);
  int*   cur_e   = (int*)alloc(N_EDGES * 4);
  int*   cur_n   = (int*)alloc(N_NODES * 4);
  int*   e_idx   = (int*)alloc(N_INC * 4);
  int*   n_idx   = (int*)alloc(N_INC * 4);
  int*   gstart  = (int*)alloc((N_GRAPHS + 1) * 4);
  float* pooled  = (float*)alloc((size_t)N_GRAPHS * HID * 4);
  float* wlinT   = (float*)alloc((size_t)HID * F_IN * 4);
  float* wcT     = (float*)alloc((size_t)HID * 512 * 4);
  float* wlkT    = (float*)alloc((size_t)ODIM * HID * 4);
  float* xg1     = (float*)alloc((size_t)512 * 2048 * 4);
  float* xg2     = (float*)alloc((size_t)512 * 2048 * 4);
  float* l1      = (float*)alloc((size_t)512 * 512 * 4);
  float* l2      = (float*)alloc((size_t)512 * 512 * 4);
  float* causal  = (float*)alloc((size_t)512 * HID * 4);
  float* hbuf    = (float*)alloc((size_t)2 * 2 * 2 * 16 * 256 * 4);  // [layer][slot][dir][b][256]
  int*   lcnt    = (int*)alloc(2 * 32 * 4);                          // [layer][dir*16+q] stamps

  (void)hipMemsetAsync(cnt_e, 0, N_EDGES * 4, stream);
  (void)hipMemsetAsync(deg,   0, N_NODES * 4, stream);
  (void)hipMemsetAsync(cur_e, 0, N_EDGES * 4, stream);
  (void)hipMemsetAsync(cur_n, 0, N_NODES * 4, stream);
  (void)hipMemsetAsync(hbuf,  0, (size_t)2 * 2 * 2 * 16 * 256 * 4, stream);
  (void)hipMemsetAsync(lcnt,  0, 2 * 32 * 4, stream);

  // CSR build
  k_count<<<(N_INC + 255) / 256, 256, 0, stream>>>(he_node, he_edge, cnt_e, deg);
  k_scan<<<1, 1024, 0, stream>>>(cnt_e, e_start, N_EDGES);
  k_scan<<<1, 1024, 0, stream>>>(deg, n_start, N_NODES);
  k_fill<<<(N_INC + 255) / 256, 256, 0, stream>>>(he_node, he_edge, e_start, n_start,
                                                  cur_e, cur_n, e_idx, n_idx);
  k_gstart<<<(N_GRAPHS + 1 + 255) / 256, 256, 0, stream>>>(batch, gstart);
  // weight transposes
  k_transpose<<<(F_IN * HID + 255) / 256, 256, 0, stream>>>(w_lin, wlinT, F_IN, HID);
  k_transpose<<<(512 * HID + 255) / 256, 256, 0, stream>>>(w_causal, wcT, 512, HID);
  k_transpose<<<(HID * ODIM + 255) / 256, 256, 0, stream>>>(w_link, wlkT, HID, ODIM);

  // xh = x @ w_lin ; eattr ; eh = eattr @ w_lin
  k_gemm<128, 8><<<dim3(HID / 128, (N_NODES + 127) / 128), 256, 0, stream>>>(
      x, wlinT, xh, N_NODES, HID, F_IN, nullptr, nullptr, 0, 0);
  k_eattr<<<N_EDGES / 4, 256, 0, stream>>>(x, he_node, e_start, e_idx, eattr);
  k_gemm<128, 8><<<dim3(HID / 128, (N_EDGES + 127) / 128), 256, 0, stream>>>(
      eattr, wlinT, eh, N_EDGES, HID, F_IN, nullptr, nullptr, 0, 0);
  // separable attention logits + softmax
  k_dot<<<N_NODES / 4, 256, 0, stream>>>(xh, att, s_n, 0, N_NODES);
  k_dot<<<N_EDGES / 4, 256, 0, stream>>>(eh, att, s_e, 1, N_EDGES);
  k_logit<<<(N_INC + 255) / 256, 256, 0, stream>>>(he_node, he_edge, s_n, s_e, alpha);
  k_softmax<<<N_EDGES / 4, 256, 0, stream>>>(e_start, e_idx, alpha);
  // two-hop propagation
  k_out_e<<<N_EDGES / 4, 256, 0, stream>>>(xh, alpha, e_start, e_idx, he_node, out_e);
  k_out_n<<<N_NODES / 4, 256, 0, stream>>>(out_e, alpha, n_start, n_idx, he_edge, bias, xh);
  // pooling
  k_pool<<<N_GRAPHS, 256, 0, stream>>>(xh, gstart, pooled);

  // LSTM layer 1
  k_gemm<64, 4><<<dim3(2048 / 64, 512 / 64), 256, 0, stream>>>(
      pooled, w_ih0, xg1, 512, 2048, HID, b_ih0, b_hh0, 0, 0);
  k_lstm2<<<32, 256, 0, stream>>>(xg1, w_hh0, l1, hbuf, lcnt, 1, 32);
  // LSTM layer 2
  k_gemm<64, 4><<<dim3(2048 / 64, 512 / 64), 256, 0, stream>>>(
      l1, w_ih1, xg2, 512, 2048, 512, b_ih1, b_hh1, 0, 0);
  k_lstm2<<<32, 256, 0, stream>>>(xg2, w_hh1, l2, hbuf + 2 * 2 * 16 * 256, lcnt + 32, 16, 1);
  // heads
  k_gemm<64, 4><<<dim3(HID / 64, 512 / 64), 256, 0, stream>>>(
      l2, wcT, causal, 512, HID, 512, b_causal, nullptr, 1, 0);
  k_gemm<64, 4><<<dim3(ODIM / 64, 512 / 64), 256, 0, stream>>>(
      causal, wlkT, out, 512, ODIM, HID, b_link, nullptr, 2, 1);
  (void)in_sizes; (void)n_in; (void)out_size; (void)ws_size;
}